// Round 19
// baseline (236.770 us; speedup 1.0000x reference)
//
#include <hip/hip_runtime.h>
#include <hip/hip_fp16.h>

// Problem constants (from reference)
constexpr int N_FRAMES   = 2000;
constexpr int BATCH      = 32;
constexpr int TARGET_LEN = 1000;
constexpr int VOCAB      = 256;
constexpr int SPH        = 8;        // 2-row steps per chunk/phase (=16 rows)
constexpr int NW         = 8;        // waves per block (2 per SIMD)
#define NEGF (-1e30f)

// addrspace(1) pointers => guaranteed global_load (vmcnt only, never flat).
typedef __attribute__((address_space(1))) const float* gcfp;
typedef __attribute__((address_space(1))) const unsigned* gcu32;

typedef float f32x2 __attribute__((ext_vector_type(2)));

#define H2F(us) __half2float(__ushort_as_half((unsigned short)(us)))

// Cross-lane shift-by-1 via DPP (pure VALU; verified R16, absmax 0.0)
//   wf_sr1 (0x138): lane n <- lane n-1  == shfl_up(x,1)
//   wf_sl1 (0x130): lane n <- lane n+1  == shfl_down(x,1)
#if __has_builtin(__builtin_amdgcn_update_dpp)
__device__ __forceinline__ float lane_up1(float x) {
    return __int_as_float(__builtin_amdgcn_update_dpp(
        0, __float_as_int(x), 0x138, 0xf, 0xf, false));
}
__device__ __forceinline__ float lane_dn1(float x) {
    return __int_as_float(__builtin_amdgcn_update_dpp(
        0, __float_as_int(x), 0x130, 0xf, 0xf, false));
}
#else
__device__ __forceinline__ float lane_up1(float x) { return __shfl_up(x, 1); }
__device__ __forceinline__ float lane_dn1(float x) { return __shfl_down(x, 1); }
#endif

// Tangent-line corr g(x)=log2(1+2^-x), x>=0 (validated R17, err<=0.024)
__device__ __forceinline__ f32x2 lse_corr(f32x2 ax) {
    const f32x2 l0 = ax * -0.5f         + 1.0f;
    const f32x2 l1 = ax * -0.33333333f  + 0.91829583f;
    const f32x2 l2 = ax * -0.2f         + 0.72192809f;
    const f32x2 l3 = ax * -0.05882353f  + 0.32275690f;
    const f32x2 l4 = ax * -0.01538462f  + 0.11467554f;
    f32x2 g;
    g.x = fmaxf(fmaxf(fmaxf(l0.x, l1.x), fmaxf(l2.x, l3.x)), fmaxf(l4.x, 0.0f));
    g.y = fmaxf(fmaxf(fmaxf(l0.y, l1.y), fmaxf(l2.y, l3.y)), fmaxf(l4.y, 0.0f));
    return g;
}
// pairwise LSE2 (tangent corr) — used for the OFF-CHAIN R coefficient only
__device__ __forceinline__ f32x2 lse2t(f32x2 X, f32x2 Y) {
    f32x2 mm; mm.x = fmaxf(X.x, Y.x); mm.y = fmaxf(X.y, Y.y);
    const f32x2 d = X - Y;
    f32x2 ax; ax.x = fabsf(d.x); ax.y = fabsf(d.y);
    return lse_corr(ax) + mm;
}
// exact 3-term LSE (log2 domain): one of d's is 0 -> s >= 1
__device__ __forceinline__ f32x2 lse3(f32x2 T2, f32x2 T1, f32x2 T0) {
    f32x2 m3;
    m3.x = fmaxf(fmaxf(T2.x, T1.x), T0.x);
    m3.y = fmaxf(fmaxf(T2.y, T1.y), T0.y);
    const f32x2 d2 = T2 - m3, d1 = T1 - m3, d0 = T0 - m3;
    f32x2 s;
    s.x = __builtin_amdgcn_exp2f(d2.x) + __builtin_amdgcn_exp2f(d1.x)
        + __builtin_amdgcn_exp2f(d0.x);
    s.y = __builtin_amdgcn_exp2f(d2.y) + __builtin_amdgcn_exp2f(d1.y)
        + __builtin_amdgcn_exp2f(d0.y);
    f32x2 r;
    r.x = m3.x + __builtin_amdgcn_logf(s.x);   // v_log_f32 == log2 (verified)
    r.y = m3.y + __builtin_amdgcn_logf(s.y);
    return r;
}

// ---------------- Phase 1: massively parallel emit gather (unchanged) --------
// emit[b][i][col] = fp16( scores[i,b,tgt[b][min(col,999)]] * log2(e) )
__global__ __launch_bounds__(256)
void gather_emit(const float* __restrict__ scores,
                 const int*   __restrict__ targets,
                 const int*   __restrict__ in_len,
                 __half*      __restrict__ emit)
{
    constexpr float L2E = 1.44269504088896340736f;
    const int i = blockIdx.x;
    const int b = blockIdx.y;
    if (i >= in_len[b]) return;
    const int t = threadIdx.x;

    const gcfp gsc = (gcfp)scores;
    const unsigned sbase = (unsigned)(i * BATCH * VOCAB + b * VOCAB);

    int tk0, tk1, tk2, tk3;
    if (t < TARGET_LEN / 4) {
        const int4 tk = *(const int4*)&targets[b * TARGET_LEN + 4 * t];
        tk0 = tk.x; tk1 = tk.y; tk2 = tk.z; tk3 = tk.w;
    } else {
        tk0 = tk1 = tk2 = tk3 = targets[b * TARGET_LEN + TARGET_LEN - 1];
    }

    const float e0 = gsc[sbase + (unsigned)tk0] * L2E;
    const float e1 = gsc[sbase + (unsigned)tk1] * L2E;
    const float e2 = gsc[sbase + (unsigned)tk2] * L2E;
    const float e3 = gsc[sbase + (unsigned)tk3] * L2E;

    const unsigned long long h0 = __half_as_ushort(__float2half_rn(e0));
    const unsigned long long h1 = __half_as_ushort(__float2half_rn(e1));
    const unsigned long long h2 = __half_as_ushort(__float2half_rn(e2));
    const unsigned long long h3 = __half_as_ushort(__float2half_rn(e3));

    const unsigned long long u = h0 | (h1 << 16) | (h2 << 32) | (h3 << 48);
    *(unsigned long long*)(emit + (((size_t)(b * N_FRAMES + i)) << 10) + 4 * t) = u;
}

// ---------------- Phase 2: 2-ROW-COMPOSED fwd+bwd DP ----------------
// One serial step = TWO lattice rows (exact algebra):
//   alpha[i+2,j] = LSE3(a[j-2]+Q, a[j-1]+R, a[j]+S),  Q=e2+e1[j-1],
//   R=e2+LSE2(e1[j-1],e1[j]), S=e2+e1[j]   (coeffs on-the-fly, OFF-chain)
// Same proven skeleton: 8 waves x 2 cols/lane, skewed chunks (8 steps=16 rows
// per barrier), DPP cross-lane, branchless folded bodies, raw s_barrier +
// lgkm-only drain. Cut row m = istart - 2*(istart>>2); fwd parity via
// closed-form alpha[r0] init (r0 = m&1).
__global__ __launch_bounds__(512)
void align_dp_fb2(const __half* __restrict__ emit,   // [B][N][1024] premult L2E
                  const int*    __restrict__ in_len,
                  const int*    __restrict__ tg_len,
                  float*        __restrict__ wsA,    // [B][1024]
                  float*        __restrict__ wsB)    // [B][1024]
{
    const int b    = blockIdx.x;
    const int t    = threadIdx.x;            // 0..511
    const int lane = t & 63;
    const int w    = t >> 6;                 // 0..7

    __shared__ f32x2 bpub[NW - 1][2][SPH];   // pre-step boundary pairs

    const int inlen  = in_len[b];
    const int istart = inlen - 1;            // 999..1999
    const int K2b    = istart >> 2;          // bwd 2-row steps
    const int m      = istart - 2 * K2b;     // cut row
    const int r0     = m & 1;                // fwd start row (0 or 1)
    const int K2f    = (m - r0) >> 1;        // fwd 2-row steps

    const gcu32 gem = (gcu32)(emit + (((size_t)b * N_FRAMES) << 10));

    if (blockIdx.y == 0) {
        // ================= FORWARD: alpha[r0] --(K2f steps)--> alpha[m] =====
        const int NCH = (K2f + SPH - 1) >> 3;
        const int tm1 = (t == 0) ? 0 : t - 1;

        float a0 = NEGF, a1 = NEGF;
        if (t == 0) {
            const float e00 = H2F(gem[0] & 0xffffu);
            if (r0 == 0) a0 = e00;
            else {
                const unsigned u = gem[512];   // row 1 cols 0,1
                a0 = H2F(u & 0xffffu) + e00;
                a1 = H2F(u >> 16) + e00;
            }
        }

        unsigned rA[SPH], rB[SPH], rC[SPH];   // e1[t], e1[t-1], e2[t]
#pragma unroll
        for (int s = 0; s < SPH; ++s) {
            const unsigned ro1 = (unsigned)(r0 + 2 * s + 1) << 9;
            rA[s] = gem[ro1 + (unsigned)t];
            rB[s] = gem[ro1 + (unsigned)tm1];
            rC[s] = gem[ro1 + 512u + (unsigned)t];
        }

        f32x2* wsA2 = (f32x2*)(wsA + (b << 10));

#define FSTEP(s, SNAPF, GUARDF)                                                 \
        {                                                                       \
            const int gs = q8 + (s);                                            \
            if (!(GUARDF) || (gs < K2f)) {                                      \
                const unsigned u1 = rA[s], u1m = rB[s], u2 = rC[s];             \
                if (!(GUARDF) || (gs + SPH < K2f)) {                            \
                    const unsigned ro1n = (unsigned)(r0 + 2 * (gs + SPH) + 1) << 9; \
                    rA[s] = gem[ro1n + (unsigned)t];                            \
                    rB[s] = gem[ro1n + (unsigned)tm1];                          \
                    rC[s] = gem[ro1n + 512u + (unsigned)t];                     \
                }                                                               \
                if (w < NW - 1 && lane == 63) {                                 \
                    f32x2 pp; pp.x = a0; pp.y = a1; dp2[s] = pp;                \
                }                                                               \
                const float d0s = lane_up1(a0), d1s = lane_up1(a1);             \
                const float e1a = H2F(u1 & 0xffffu), e1b = H2F(u1 >> 16);       \
                const float e1p = (t == 0) ? NEGF : H2F(u1m >> 16);             \
                const float e2a = H2F(u2 & 0xffffu), e2b = H2F(u2 >> 16);       \
                f32x2 Lx, Rx; Lx.x = e1p; Lx.y = e1a; Rx.x = e1a; Rx.y = e1b;   \
                const f32x2 ls = lse2t(Lx, Rx);                                 \
                f32x2 E2; E2.x = e2a; E2.y = e2b;                               \
                f32x2 Qp; Qp.x = e2a + e1p; Qp.y = e2b + e1a;                   \
                const f32x2 Rp = E2 + ls;                                       \
                f32x2 Sp; Sp.x = e2a + e1a; Sp.y = e2b + e1b;                   \
                const float am2 = (lane == 0) ? Bv##s.x : d0s;                  \
                const float am1 = (lane == 0) ? Bv##s.y : d1s;                  \
                f32x2 A2v; A2v.x = am2; A2v.y = am1;                            \
                f32x2 A1v; A1v.x = am1; A1v.y = a0;                             \
                f32x2 A0v; A0v.x = a0;  A0v.y = a1;                             \
                const f32x2 res = lse3(A2v + Qp, A1v + Rp, A0v + Sp);           \
                if (SNAPF) { if (gs == K2f - 1) wsA2[t] = res; }                \
                a0 = res.x; a1 = res.y;                                         \
            }                                                                   \
        }

#define FBODY(SNAPF, GUARDF)                                                    \
        { FSTEP(0, SNAPF, GUARDF) FSTEP(1, SNAPF, GUARDF)                       \
          FSTEP(2, SNAPF, GUARDF) FSTEP(3, SNAPF, GUARDF)                       \
          FSTEP(4, SNAPF, GUARDF) FSTEP(5, SNAPF, GUARDF)                       \
          FSTEP(6, SNAPF, GUARDF) FSTEP(7, SNAPF, GUARDF) }

        const int NPH = NCH + NW - 1;
        for (int p = 0; p < NPH; ++p) {
            const int q = p - w;
            if (q >= 0 && q < NCH) {
                const int q8  = q << 3;
                const int par = q & 1;
                f32x2 Bv0 = {NEGF, NEGF}, Bv1 = {NEGF, NEGF},
                      Bv2 = {NEGF, NEGF}, Bv3 = {NEGF, NEGF},
                      Bv4 = {NEGF, NEGF}, Bv5 = {NEGF, NEGF},
                      Bv6 = {NEGF, NEGF}, Bv7 = {NEGF, NEGF};
                if (w > 0) {
                    const f32x2* vp2 = &bpub[w - 1][par][0];
                    Bv0 = vp2[0]; Bv1 = vp2[1]; Bv2 = vp2[2]; Bv3 = vp2[3];
                    Bv4 = vp2[4]; Bv5 = vp2[5]; Bv6 = vp2[6]; Bv7 = vp2[7];
                }
                f32x2* dp2 = &bpub[(w < NW - 1) ? w : 0][par][0];

                if (q < NCH - 2)       FBODY(false, false)
                else if (q == NCH - 1) FBODY(true,  true)
                else                   FBODY(false, true)
            }
            asm volatile("s_waitcnt lgkmcnt(0)" ::: "memory");
            __builtin_amdgcn_s_barrier();
            asm volatile("" ::: "memory");
        }
#undef FBODY
#undef FSTEP
    } else {
        // ================= BACKWARD: beta[istart] --(K2b steps)--> beta[m] ==
        const int tlen = tg_len[b];
        const int NCH  = (K2b + SPH - 1) >> 3;
        const int tp1  = (t == 511) ? 511 : t + 1;
        const int fth  = (tlen - 1) >> 1;
        const int fcc  = (tlen - 1) & 1;

        float b0 = NEGF, b1 = NEGF;
        if (t == fth) { if (fcc == 0) b0 = 0.0f; else b1 = 0.0f; }

        unsigned rA[SPH], rB[SPH], rC[SPH], rD[SPH]; // e1[t],e1[t+1],e2[t],e2[t+1]
#pragma unroll
        for (int s = 0; s < SPH; ++s) {
            const unsigned base = (unsigned)(istart - 2 * s) << 9;  // row ro2
            rA[s] = gem[base - 512u + (unsigned)t];
            rB[s] = gem[base - 512u + (unsigned)tp1];
            rC[s] = gem[base + (unsigned)t];
            rD[s] = gem[base + (unsigned)tp1];
        }

        f32x2* wsB2 = (f32x2*)(wsB + (b << 10));

#define BSTEP(s, SNAPF, GUARDF)                                                 \
        {                                                                       \
            const int gs = q8 + (s);                                            \
            if (!(GUARDF) || (gs < K2b)) {                                      \
                const unsigned u1 = rA[s], u1n = rB[s], u2 = rC[s], u2n = rD[s];\
                if (!(GUARDF) || (gs + SPH < K2b)) {                            \
                    const unsigned ro2n = (unsigned)(istart - 2 * (gs + SPH)) << 9; \
                    rA[s] = gem[ro2n - 512u + (unsigned)t];                     \
                    rB[s] = gem[ro2n - 512u + (unsigned)tp1];                   \
                    rC[s] = gem[ro2n + (unsigned)t];                            \
                    rD[s] = gem[ro2n + (unsigned)tp1];                          \
                }                                                               \
                if (w > 0 && lane == 0) {                                       \
                    f32x2 pp; pp.x = b0; pp.y = b1; dp2[s] = pp;                \
                }                                                               \
                const float dn0 = lane_dn1(b0), dn1 = lane_dn1(b1);             \
                const float e1a = H2F(u1 & 0xffffu), e1b = H2F(u1 >> 16);       \
                const float e1n = H2F(u1n & 0xffffu);                           \
                const float e2a = H2F(u2 & 0xffffu), e2b = H2F(u2 >> 16);       \
                const float e2n0 = H2F(u2n & 0xffffu), e2n1 = H2F(u2n >> 16);   \
                f32x2 Lx, Rx; Lx.x = e1a; Lx.y = e1b; Rx.x = e1b; Rx.y = e1n;   \
                const f32x2 ls = lse2t(Lx, Rx);                                 \
                f32x2 Ew; Ew.x = e2b; Ew.y = e2n0;                              \
                const f32x2 Rp = Ew + ls;                                       \
                f32x2 Sp; Sp.x = e1a + e2a;  Sp.y = e1b + e2b;                  \
                f32x2 Qp; Qp.x = e1b + e2n0; Qp.y = e1n + e2n1;                 \
                const float bn0 = (lane == 63) ? Bv##s.x : dn0;                 \
                const float bn1 = (lane == 63) ? Bv##s.y : dn1;                 \
                f32x2 B0v; B0v.x = b0;  B0v.y = b1;                             \
                f32x2 B1v; B1v.x = b1;  B1v.y = bn0;                            \
                f32x2 B2v; B2v.x = bn0; B2v.y = bn1;                            \
                const f32x2 res = lse3(B2v + Qp, B1v + Rp, B0v + Sp);           \
                if (SNAPF) { if (gs == K2b - 1) wsB2[t] = res; }                \
                b0 = res.x; b1 = res.y;                                         \
            }                                                                   \
        }

#define BBODY(SNAPF, GUARDF)                                                    \
        { BSTEP(0, SNAPF, GUARDF) BSTEP(1, SNAPF, GUARDF)                       \
          BSTEP(2, SNAPF, GUARDF) BSTEP(3, SNAPF, GUARDF)                       \
          BSTEP(4, SNAPF, GUARDF) BSTEP(5, SNAPF, GUARDF)                       \
          BSTEP(6, SNAPF, GUARDF) BSTEP(7, SNAPF, GUARDF) }

        const int NPH = NCH + NW - 1;
        for (int p = 0; p < NPH; ++p) {
            const int q = p - (NW - 1 - w);   // wave 7 leads (right->left flow)
            if (q >= 0 && q < NCH) {
                const int q8  = q << 3;
                const int par = q & 1;
                f32x2 Bv0 = {NEGF, NEGF}, Bv1 = {NEGF, NEGF},
                      Bv2 = {NEGF, NEGF}, Bv3 = {NEGF, NEGF},
                      Bv4 = {NEGF, NEGF}, Bv5 = {NEGF, NEGF},
                      Bv6 = {NEGF, NEGF}, Bv7 = {NEGF, NEGF};
                if (w < NW - 1) {
                    const f32x2* vp2 = &bpub[w][par][0];
                    Bv0 = vp2[0]; Bv1 = vp2[1]; Bv2 = vp2[2]; Bv3 = vp2[3];
                    Bv4 = vp2[4]; Bv5 = vp2[5]; Bv6 = vp2[6]; Bv7 = vp2[7];
                }
                f32x2* dp2 = &bpub[(w > 0) ? w - 1 : 0][par][0];

                if (q < NCH - 2)       BBODY(false, false)
                else if (q == NCH - 1) BBODY(true,  true)
                else                   BBODY(false, true)
            }
            asm volatile("s_waitcnt lgkmcnt(0)" ::: "memory");
            __builtin_amdgcn_s_barrier();
            asm volatile("" ::: "memory");
        }
#undef BBODY
#undef BSTEP
    }
}

// ---------------- Phase 3: LSE join over the cut row ----------------
__global__ __launch_bounds__(512)
void lse_combine(const float* __restrict__ wsA, const float* __restrict__ wsB,
                 float* __restrict__ ws_final)
{
    constexpr float LN2 = 0.69314718055994530942f;
    const int b = blockIdx.x, t = threadIdx.x, lane = t & 63, w = t >> 6;
    __shared__ float red[8];

    const float* A  = wsA + (b << 10);
    const float* Bv = wsB + (b << 10);
    const float v0 = A[2 * t]     + Bv[2 * t];
    const float v1 = A[2 * t + 1] + Bv[2 * t + 1];

    float mx = fmaxf(v0, v1);
#pragma unroll
    for (int off = 1; off < 64; off <<= 1) mx = fmaxf(mx, __shfl_xor(mx, off));
    if (lane == 0) red[w] = mx;
    __syncthreads();
    float gm = red[0];
#pragma unroll
    for (int k = 1; k < 8; ++k) gm = fmaxf(gm, red[k]);

    float s = __builtin_amdgcn_exp2f(v0 - gm) + __builtin_amdgcn_exp2f(v1 - gm);
#pragma unroll
    for (int off = 1; off < 64; off <<= 1) s += __shfl_xor(s, off);
    __syncthreads();
    if (lane == 0) red[w] = s;
    __syncthreads();
    if (t == 0) {
        float tot = red[0];
#pragma unroll
        for (int k = 1; k < 8; ++k) tot += red[k];
        ws_final[b] = (gm + __builtin_amdgcn_logf(tot)) * LN2;
    }
}

// Final scalar: out = -sum(ws_final)/BATCH. Unconditional write.
__global__ void reduce_kernel(const float* __restrict__ ws_final, float* __restrict__ out)
{
    if (threadIdx.x == 0 && blockIdx.x == 0) {
        float s = 0.0f;
        for (int b = 0; b < BATCH; ++b) s += ws_final[b];
        out[0] = -s / (float)BATCH;
    }
}

// ---------------- Fallback (verified R3 kernel) if ws too small ----------------
#define CELL(dst, A, U, E)                                            \
    {                                                                 \
        const float m_ = fmaxf((A), (U));                             \
        const float d_ = (A) - (U);                                   \
        const float p_ = __builtin_amdgcn_exp2f(-fabsf(d_));          \
        const float l_ = __builtin_amdgcn_logf(1.0f + p_);            \
        (dst) = fmaf((E), L2E, m_ + l_);                              \
    }

__global__ __launch_bounds__(256)
void align_dp4(const float* __restrict__ scores,
               const int*   __restrict__ targets,
               const int*   __restrict__ in_len,
               const int*   __restrict__ tg_len,
               float*       __restrict__ ws_final)
{
    constexpr float L2E = 1.44269504088896340736f;
    constexpr float LN2 = 0.69314718055994530942f;

    const int b    = blockIdx.x;
    const int t    = threadIdx.x;
    const int lane = t & 63;
    const int w    = t >> 6;

    __shared__ float elds[4][VOCAB];
    __shared__ float bnd[2][8];

    const int inlen = in_len[b];
    const int tlen  = tg_len[b];

    const gcfp gsc = (gcfp)scores;
    const unsigned base = (unsigned)(b * VOCAB);
    constexpr unsigned ROWW = (unsigned)(BATCH * VOCAB);

    int tok[4];
#pragma unroll
    for (int c = 0; c < 4; ++c) {
        const int col = t * 4 + c;
        tok[c] = targets[b * TARGET_LEN + (col < TARGET_LEN ? col : TARGET_LEN - 1)];
    }

    float prev[4];
#pragma unroll
    for (int c = 0; c < 4; ++c) prev[c] = NEGF;
    if (t == 0) prev[0] = gsc[base + (unsigned)tok[0]] * L2E;

    elds[1][t] = gsc[1u * ROWW + base + (unsigned)t];
    elds[2][t] = gsc[2u * ROWW + base + (unsigned)t];
    if (lane == 63) bnd[0][w] = NEGF;

    float g[4];
    g[3] = gsc[3u * ROWW + base + (unsigned)t];
    g[0] = gsc[4u * ROWW + base + (unsigned)t];
    g[1] = gsc[5u * ROWW + base + (unsigned)t];
    g[2] = gsc[6u * ROWW + base + (unsigned)t];

    const int fth = (tlen - 1) >> 2;
    const int fcc = (tlen - 1) & 3;

#define STEP(K)                                                                    \
    {                                                                              \
        const int i = ib + (K);                                                    \
        if (i < N_FRAMES) {                                                        \
            asm volatile("s_waitcnt lgkmcnt(0)" ::: "memory");                     \
            __builtin_amdgcn_s_barrier();                                          \
            asm volatile("" ::: "memory");                                         \
            const int sl = i & 3;                                                  \
            const float ec0 = elds[sl][tok[0]];                                    \
            const float ec1 = elds[sl][tok[1]];                                    \
            const float ec2 = elds[sl][tok[2]];                                    \
            const float ec3 = elds[sl][tok[3]];                                    \
            const float fromLds = (w > 0) ? bnd[(i - 1) & 1][w - 1] : NEGF;        \
            if (i + 2 < N_FRAMES) elds[(i + 2) & 3][t] = g[((K) + 3) & 3];         \
            if (i + 6 < N_FRAMES)                                                  \
                g[((K) + 3) & 3] = gsc[(unsigned)(i + 6) * ROWW + base + (unsigned)t]; \
            const float sh   = __shfl_up(prev[3], 1);                              \
            const float left = (lane == 0) ? fromLds : sh;                         \
            float cur0, cur1, cur2, cur3;                                          \
            CELL(cur0, left,    prev[0], ec0);                                     \
            CELL(cur1, prev[0], prev[1], ec1);                                     \
            CELL(cur2, prev[1], prev[2], ec2);                                     \
            CELL(cur3, prev[2], prev[3], ec3);                                     \
            if (lane == 63) bnd[i & 1][w] = cur3;                                  \
            if (i == inlen - 1 && t == fth) {                                      \
                const float v = (fcc == 0) ? cur0 : (fcc == 1) ? cur1              \
                              : (fcc == 2) ? cur2 : cur3;                          \
                ws_final[b] = v * LN2;                                             \
            }                                                                      \
            prev[0] = cur0; prev[1] = cur1; prev[2] = cur2; prev[3] = cur3;        \
        }                                                                          \
    }

    for (int ib = 1; ib < N_FRAMES; ib += 4) {
        STEP(0) STEP(1) STEP(2) STEP(3)
    }
#undef STEP
}

extern "C" void kernel_launch(void* const* d_in, const int* in_sizes, int n_in,
                              void* d_out, int out_size, void* d_ws, size_t ws_size,
                              hipStream_t stream)
{
    const float* scores  = (const float*)d_in[0];
    const int*   targets = (const int*)  d_in[1];
    const int*   in_len  = (const int*)  d_in[2];
    const int*   tg_len  = (const int*)  d_in[3];
    float*       out     = (float*)d_out;
    float*       ws_fin  = (float*)d_ws;                     // [0,256): per-batch finals

    const size_t emit_bytes = (size_t)BATCH * N_FRAMES * 1024 * sizeof(__half);
    const size_t wsA_off  = 4096;
    const size_t wsB_off  = wsA_off + (size_t)BATCH * 1024 * sizeof(float);   // +128KB
    const size_t emit_off = wsB_off + (size_t)BATCH * 1024 * sizeof(float);   // +128KB
    const size_t need = emit_off + emit_bytes;

    if (ws_size >= need) {
        __half* emit = (__half*)((char*)d_ws + emit_off);
        float*  wsA  = (float*)((char*)d_ws + wsA_off);
        float*  wsB  = (float*)((char*)d_ws + wsB_off);
        dim3 ggrid(N_FRAMES, BATCH);
        gather_emit<<<ggrid, 256, 0, stream>>>(scores, targets, in_len, emit);
        align_dp_fb2<<<dim3(BATCH, 2), 512, 0, stream>>>(emit, in_len, tg_len, wsA, wsB);
        lse_combine<<<BATCH, 512, 0, stream>>>(wsA, wsB, ws_fin);
    } else {
        align_dp4<<<BATCH, 256, 0, stream>>>(scores, targets, in_len, tg_len, ws_fin);
    }
    reduce_kernel<<<1, 64, 0, stream>>>(ws_fin, out);
}

// Round 20
// 195.306 us; speedup vs baseline: 1.2123x; 1.2123x over previous
//
#include <hip/hip_runtime.h>
#include <hip/hip_fp16.h>

// Problem constants (from reference)
constexpr int N_FRAMES   = 2000;
constexpr int BATCH      = 32;
constexpr int TARGET_LEN = 1000;
constexpr int VOCAB      = 256;
constexpr int CH         = 16;       // rows per chunk/phase (R13-proven)
constexpr int NW         = 8;        // waves per block (2 per SIMD)
#define NEGF (-1e30f)

// addrspace(1) pointers => guaranteed global_load (vmcnt only, never flat).
typedef __attribute__((address_space(1))) const float* gcfp;
typedef __attribute__((address_space(1))) const unsigned* gcu32;

typedef float f32x2 __attribute__((ext_vector_type(2)));

#define H2F(us) __half2float(__ushort_as_half((unsigned short)(us)))

// Cross-lane shift-by-1 via DPP (pure VALU, NO LDS pipe / lgkmcnt).
//   wf_sr1 (0x138): lane n <- lane n-1  == shfl_up(x,1)
//   wf_sl1 (0x130): lane n <- lane n+1  == shfl_down(x,1)
// (verified R16, absmax 0.0)
#if __has_builtin(__builtin_amdgcn_update_dpp)
__device__ __forceinline__ float lane_up1(float x) {
    return __int_as_float(__builtin_amdgcn_update_dpp(
        0, __float_as_int(x), 0x138, 0xf, 0xf, false));
}
__device__ __forceinline__ float lane_dn1(float x) {
    return __int_as_float(__builtin_amdgcn_update_dpp(
        0, __float_as_int(x), 0x130, 0xf, 0xf, false));
}
#else
__device__ __forceinline__ float lane_up1(float x) { return __shfl_up(x, 1); }
__device__ __forceinline__ float lane_dn1(float x) { return __shfl_down(x, 1); }
#endif

// log2(1+x) on [0,1], degree-5 minimax (validated R9-R16, absmax 0.0),
// Estrin form: dependency depth 4.
__device__ __forceinline__ f32x2 l21p(f32x2 x) {
    const f32x2 x2 = x * x;
    const f32x2 x4 = x2 * x2;
    f32x2 lo = x * 1.44196727f;
    const f32x2 Bq = x * 0.4176245f  - 0.7096745f;
    const f32x2 Cq = x * 0.0464048f  - 0.1963066f;
    lo = x2 * Bq + lo;
    return x4 * Cq + lo;
}
// c = E + max(A,U) + log2(1+2^-|A-U|)
__device__ __forceinline__ f32x2 lse_e(f32x2 A, f32x2 U, f32x2 E) {
    f32x2 m; m.x = fmaxf(A.x, U.x); m.y = fmaxf(A.y, U.y);
    const f32x2 d = A - U;
    f32x2 x;
    x.x = __builtin_amdgcn_exp2f(-fabsf(d.x));
    x.y = __builtin_amdgcn_exp2f(-fabsf(d.y));
    const f32x2 s = E + m;
    return l21p(x) + s;
}
// c = max(A,U) + log2(1+2^-|A-U|)
__device__ __forceinline__ f32x2 lse_core(f32x2 A, f32x2 U) {
    f32x2 m; m.x = fmaxf(A.x, U.x); m.y = fmaxf(A.y, U.y);
    const f32x2 d = A - U;
    f32x2 x;
    x.x = __builtin_amdgcn_exp2f(-fabsf(d.x));
    x.y = __builtin_amdgcn_exp2f(-fabsf(d.y));
    return l21p(x) + m;
}

// ---------------- Phase 1: massively parallel emit gather ----------------
// emit[b][i][col] = fp16( scores[i,b,tgt[b][min(col,999)]] * log2(e) )
// Rows i >= in_len[b] are never read by the DP -> skip (~25% traffic).
__global__ __launch_bounds__(256)
void gather_emit(const float* __restrict__ scores,
                 const int*   __restrict__ targets,
                 const int*   __restrict__ in_len,
                 __half*      __restrict__ emit)
{
    constexpr float L2E = 1.44269504088896340736f;
    const int i = blockIdx.x;
    const int b = blockIdx.y;
    if (i >= in_len[b]) return;
    const int t = threadIdx.x;

    const gcfp gsc = (gcfp)scores;
    const unsigned sbase = (unsigned)(i * BATCH * VOCAB + b * VOCAB);

    int tk0, tk1, tk2, tk3;
    if (t < TARGET_LEN / 4) {
        const int4 tk = *(const int4*)&targets[b * TARGET_LEN + 4 * t];
        tk0 = tk.x; tk1 = tk.y; tk2 = tk.z; tk3 = tk.w;
    } else {
        tk0 = tk1 = tk2 = tk3 = targets[b * TARGET_LEN + TARGET_LEN - 1];
    }

    const float e0 = gsc[sbase + (unsigned)tk0] * L2E;
    const float e1 = gsc[sbase + (unsigned)tk1] * L2E;
    const float e2 = gsc[sbase + (unsigned)tk2] * L2E;
    const float e3 = gsc[sbase + (unsigned)tk3] * L2E;

    const unsigned long long h0 = __half_as_ushort(__float2half_rn(e0));
    const unsigned long long h1 = __half_as_ushort(__float2half_rn(e1));
    const unsigned long long h2 = __half_as_ushort(__float2half_rn(e2));
    const unsigned long long h3 = __half_as_ushort(__float2half_rn(e3));

    const unsigned long long u = h0 | (h1 << 16) | (h2 << 32) | (h3 << 48);
    *(unsigned long long*)(emit + (((size_t)(b * N_FRAMES + i)) << 10) + 4 * t) = u;
}

// ---------------- Phase 2: forward+backward halves, one launch ----------------
// grid (BATCH, 2): y==0 forward rows 1..m -> wsA = alpha[m,*];
//                  y==1 backward rows inlen-2..m -> wsB = beta[m,*].
// R13/R16-verified skeleton (CH=16): 8 waves x 2 cols/lane, deterministic
// skewed chunks, branchless folded bodies, pk cells, DPP cross-lane, raw
// s_barrier + lgkm-only drain per phase. (Byte-identical to R16's DP.)
__global__ __launch_bounds__(512)
void align_dp_fb(const __half* __restrict__ emit,   // [B][N][1024] premult L2E
                 const int*    __restrict__ in_len,
                 const int*    __restrict__ tg_len,
                 float*        __restrict__ wsA,    // [B][1024]
                 float*        __restrict__ wsB)    // [B][1024]
{
    const int b    = blockIdx.x;
    const int t    = threadIdx.x;            // 0..511
    const int lane = t & 63;
    const int w    = t >> 6;                 // 0..7

    __shared__ float bpub[NW - 1][2][CH];

    const int inlen = in_len[b];
    const int m     = (inlen - 1) >> 1;      // cut row (499..999)

    const gcu32 gem = (gcu32)(emit + (((size_t)b * N_FRAMES) << 10));

    if (blockIdx.y == 0) {
        // ================= FORWARD: alpha rows 1..m =================
        const int NCHf = (m + CH - 1) / CH;
        float p0 = NEGF, p1 = NEGF;
        if (t == 0) p0 = H2F(gem[0] & 0xffffu);

        unsigned ring[CH];
#pragma unroll
        for (int r = 0; r < CH; ++r) ring[r] = gem[(unsigned)((1 + r) << 9) + (unsigned)t];

        float shprev = NEGF, carry = NEGF;
        f32x2* wsA2 = (f32x2*)(wsA + (b << 10));

        // all rows/refills in-range (i <= m+15, +16 <= inlen-1): no guards
#define FROWX(r, SNAPF, Bv, Ov)                                                 \
        {                                                                       \
            const int i = i0 + (r);                                             \
            const unsigned u = ring[r];                                         \
            ring[r] = gem[(unsigned)((i + CH) << 9) + (unsigned)t];             \
            f32x2 E; E.x = H2F(u & 0xffffu); E.y = H2F(u >> 16);                \
            f32x2 A; A.x = (lane == 0) ? (Bv) : shprev; A.y = p0;               \
            f32x2 U; U.x = p0; U.y = p1;                                        \
            const f32x2 c = lse_e(A, U, E);                                     \
            shprev = lane_up1(c.y);                                             \
            (Ov) = c.y;                                                         \
            if (SNAPF) { if (i == m) wsA2[t] = c; }                             \
            p0 = c.x; p1 = c.y;                                                 \
        }

#define FBODY(SNAPF)                                                            \
        {                                                                       \
            FROWX(0,  SNAPF, B0,  o0)  FROWX(1,  SNAPF, B1,  o1)                \
            FROWX(2,  SNAPF, B2,  o2)  FROWX(3,  SNAPF, B3,  o3)                \
            FROWX(4,  SNAPF, B4,  o4)  FROWX(5,  SNAPF, B5,  o5)                \
            FROWX(6,  SNAPF, B6,  o6)  FROWX(7,  SNAPF, B7,  o7)                \
            FROWX(8,  SNAPF, B8,  o8)  FROWX(9,  SNAPF, B9,  o9)                \
            FROWX(10, SNAPF, B10, o10) FROWX(11, SNAPF, B11, o11)               \
            FROWX(12, SNAPF, B12, o12) FROWX(13, SNAPF, B13, o13)               \
            FROWX(14, SNAPF, B14, o14) FROWX(15, SNAPF, B15, o15)               \
        }

        const int NPHf = NCHf + NW - 1;
        for (int p = 0; p < NPHf; ++p) {
            const int q = p - w;
            if (q >= 0 && q < NCHf) {
                const int i0  = 1 + q * CH;
                const int par = q & 1;

                float B0 = NEGF, B1 = NEGF, B2 = NEGF, B3 = NEGF,
                      B4 = NEGF, B5 = NEGF, B6 = NEGF, B7 = NEGF,
                      B8 = NEGF, B9 = NEGF, B10 = NEGF, B11 = NEGF,
                      B12 = NEGF, B13 = NEGF, B14 = NEGF, B15 = NEGF;
                if (w > 0) {
                    const float* vp = &bpub[w - 1][par][0];
                    B0 = carry;
                    B1  = vp[0];  B2  = vp[1];  B3  = vp[2];  B4  = vp[3];
                    B5  = vp[4];  B6  = vp[5];  B7  = vp[6];  B8  = vp[7];
                    B9  = vp[8];  B10 = vp[9];  B11 = vp[10]; B12 = vp[11];
                    B13 = vp[12]; B14 = vp[13]; B15 = vp[14];
                    carry = vp[15];
                }

                float o0, o1, o2, o3, o4, o5, o6, o7,
                      o8, o9, o10, o11, o12, o13, o14, o15;

                if (q == NCHf - 1) FBODY(true) else FBODY(false)

                if (w < NW - 1 && lane == 63) {
                    float* dp = &bpub[w][par][0];
                    dp[0]  = o0;  dp[1]  = o1;  dp[2]  = o2;  dp[3]  = o3;
                    dp[4]  = o4;  dp[5]  = o5;  dp[6]  = o6;  dp[7]  = o7;
                    dp[8]  = o8;  dp[9]  = o9;  dp[10] = o10; dp[11] = o11;
                    dp[12] = o12; dp[13] = o13; dp[14] = o14; dp[15] = o15;
                }
            }
            asm volatile("s_waitcnt lgkmcnt(0)" ::: "memory");
            __builtin_amdgcn_s_barrier();
            asm volatile("" ::: "memory");
        }
#undef FBODY
#undef FROWX
    } else {
        // ================= BACKWARD: beta rows inlen-2..m =================
        const int tlen   = tg_len[b];
        const int istart = inlen - 1;
        const int NCHb   = (istart - m + CH - 1) / CH;
        const int fth    = (tlen - 1) >> 1;
        const int fcc    = (tlen - 1) & 1;

        float p0 = NEGF, p1 = NEGF;
        if (t == fth) { if (fcc == 0) p0 = 0.0f; else p1 = 0.0f; }

        unsigned ring[CH];
#pragma unroll
        for (int r = 0; r < CH; ++r)
            ring[r] = gem[(unsigned)((istart - r) << 9) + (unsigned)t];

        f32x2* wsB2 = (f32x2*)(wsB + (b << 10));

        // beta[i,j] = LSE(x_j, x_{j+1}), x_j = e[i+1,j] + beta[i+1,j].
        // x at row start -> DPP shift down; publish x.x (lane0). Junk rows
        // below m (tail) compute after snapshot; refills >= m-2CH+2 >= 0.
#define BROWX(r, SNAPF, Bv, Ov)                                                 \
        {                                                                       \
            const int i = i0 - (r);                                             \
            const unsigned u = ring[r];                                         \
            ring[r] = gem[(unsigned)((i + 1 - CH) << 9) + (unsigned)t];         \
            f32x2 E; E.x = H2F(u & 0xffffu); E.y = H2F(u >> 16);                \
            f32x2 P; P.x = p0; P.y = p1;                                        \
            const f32x2 x = E + P;                                              \
            const float sh = lane_dn1(x.x);                                     \
            (Ov) = x.x;                                                         \
            const float xR = (lane == 63) ? (Bv) : sh;                          \
            f32x2 A; A.x = x.x; A.y = x.y;                                      \
            f32x2 U; U.x = x.y; U.y = xR;                                       \
            const f32x2 c = lse_core(A, U);                                     \
            if (SNAPF) { if (i == m) wsB2[t] = c; }                             \
            p0 = c.x; p1 = c.y;                                                 \
        }

#define BBODY(SNAPF)                                                            \
        {                                                                       \
            BROWX(0,  SNAPF, B0,  o0)  BROWX(1,  SNAPF, B1,  o1)                \
            BROWX(2,  SNAPF, B2,  o2)  BROWX(3,  SNAPF, B3,  o3)                \
            BROWX(4,  SNAPF, B4,  o4)  BROWX(5,  SNAPF, B5,  o5)                \
            BROWX(6,  SNAPF, B6,  o6)  BROWX(7,  SNAPF, B7,  o7)                \
            BROWX(8,  SNAPF, B8,  o8)  BROWX(9,  SNAPF, B9,  o9)                \
            BROWX(10, SNAPF, B10, o10) BROWX(11, SNAPF, B11, o11)               \
            BROWX(12, SNAPF, B12, o12) BROWX(13, SNAPF, B13, o13)               \
            BROWX(14, SNAPF, B14, o14) BROWX(15, SNAPF, B15, o15)               \
        }

        const int NPHb = NCHb + NW - 1;
        for (int p = 0; p < NPHb; ++p) {
            const int q = p - (NW - 1 - w);   // wave 7 leads (info flows right->left)
            if (q >= 0 && q < NCHb) {
                const int i0  = istart - 1 - q * CH;
                const int par = q & 1;

                float B0 = NEGF, B1 = NEGF, B2 = NEGF, B3 = NEGF,
                      B4 = NEGF, B5 = NEGF, B6 = NEGF, B7 = NEGF,
                      B8 = NEGF, B9 = NEGF, B10 = NEGF, B11 = NEGF,
                      B12 = NEGF, B13 = NEGF, B14 = NEGF, B15 = NEGF;
                if (w < NW - 1) {   // consume right wave's lane-0 x values
                    const float* vp = &bpub[w][par][0];
                    B0  = vp[0];  B1  = vp[1];  B2  = vp[2];  B3  = vp[3];
                    B4  = vp[4];  B5  = vp[5];  B6  = vp[6];  B7  = vp[7];
                    B8  = vp[8];  B9  = vp[9];  B10 = vp[10]; B11 = vp[11];
                    B12 = vp[12]; B13 = vp[13]; B14 = vp[14]; B15 = vp[15];
                }

                float o0, o1, o2, o3, o4, o5, o6, o7,
                      o8, o9, o10, o11, o12, o13, o14, o15;

                if (q == NCHb - 1) BBODY(true) else BBODY(false)

                if (w > 0 && lane == 0) {     // publish for left wave
                    float* dp = &bpub[w - 1][par][0];
                    dp[0]  = o0;  dp[1]  = o1;  dp[2]  = o2;  dp[3]  = o3;
                    dp[4]  = o4;  dp[5]  = o5;  dp[6]  = o6;  dp[7]  = o7;
                    dp[8]  = o8;  dp[9]  = o9;  dp[10] = o10; dp[11] = o11;
                    dp[12] = o12; dp[13] = o13; dp[14] = o14; dp[15] = o15;
                }
            }
            asm volatile("s_waitcnt lgkmcnt(0)" ::: "memory");
            __builtin_amdgcn_s_barrier();
            asm volatile("" ::: "memory");
        }
#undef BBODY
#undef BROWX
    }
}

// ---------------- Phase 3: LSE join + FUSED final reduce ----------------
// ws_final[b] = ln2 * log2 sum_j 2^( alphaB[m,j] + betaB[m,j] );
// the LAST finishing block (device-scope counter) computes
// out[0] = -sum_b ws_final[b] / BATCH. Counter is memset to 0 per launch.
__global__ __launch_bounds__(512)
void lse_combine(const float* __restrict__ wsA, const float* __restrict__ wsB,
                 float* __restrict__ ws_final, unsigned* __restrict__ counter,
                 float* __restrict__ out)
{
    constexpr float LN2 = 0.69314718055994530942f;
    const int b = blockIdx.x, t = threadIdx.x, lane = t & 63, w = t >> 6;
    __shared__ float red[8];

    const float* A  = wsA + (b << 10);
    const float* Bv = wsB + (b << 10);
    const float v0 = A[2 * t]     + Bv[2 * t];
    const float v1 = A[2 * t + 1] + Bv[2 * t + 1];

    float mx = fmaxf(v0, v1);
#pragma unroll
    for (int off = 1; off < 64; off <<= 1) mx = fmaxf(mx, __shfl_xor(mx, off));
    if (lane == 0) red[w] = mx;
    __syncthreads();
    float gm = red[0];
#pragma unroll
    for (int k = 1; k < 8; ++k) gm = fmaxf(gm, red[k]);

    float s = __builtin_amdgcn_exp2f(v0 - gm) + __builtin_amdgcn_exp2f(v1 - gm);
#pragma unroll
    for (int off = 1; off < 64; off <<= 1) s += __shfl_xor(s, off);
    __syncthreads();
    if (lane == 0) red[w] = s;
    __syncthreads();
    if (t == 0) {
        float tot = red[0];
#pragma unroll
        for (int k = 1; k < 8; ++k) tot += red[k];
        ws_final[b] = (gm + __builtin_amdgcn_logf(tot)) * LN2;

        __threadfence();                               // release ws_final[b]
        const unsigned old = atomicAdd(counter, 1u);   // device-scope
        if (old == (unsigned)(BATCH - 1)) {            // last block finalizes
            __threadfence();                           // acquire others' writes
            const volatile float* vf = (const volatile float*)ws_final;
            float ssum = 0.0f;
            for (int k = 0; k < BATCH; ++k) ssum += vf[k];
            out[0] = -ssum / (float)BATCH;
        }
    }
}

// Final scalar (fallback path only).
__global__ void reduce_kernel(const float* __restrict__ ws_final, float* __restrict__ out)
{
    if (threadIdx.x == 0 && blockIdx.x == 0) {
        float s = 0.0f;
        for (int b = 0; b < BATCH; ++b) s += ws_final[b];
        out[0] = -s / (float)BATCH;
    }
}

// ---------------- Fallback (verified R3 kernel) if ws too small ----------------
#define CELL(dst, A, U, E)                                            \
    {                                                                 \
        const float m_ = fmaxf((A), (U));                             \
        const float d_ = (A) - (U);                                   \
        const float p_ = __builtin_amdgcn_exp2f(-fabsf(d_));          \
        const float l_ = __builtin_amdgcn_logf(1.0f + p_);            \
        (dst) = fmaf((E), L2E, m_ + l_);                              \
    }

__global__ __launch_bounds__(256)
void align_dp4(const float* __restrict__ scores,
               const int*   __restrict__ targets,
               const int*   __restrict__ in_len,
               const int*   __restrict__ tg_len,
               float*       __restrict__ ws_final)
{
    constexpr float L2E = 1.44269504088896340736f;
    constexpr float LN2 = 0.69314718055994530942f;

    const int b    = blockIdx.x;
    const int t    = threadIdx.x;
    const int lane = t & 63;
    const int w    = t >> 6;

    __shared__ float elds[4][VOCAB];
    __shared__ float bnd[2][8];

    const int inlen = in_len[b];
    const int tlen  = tg_len[b];

    const gcfp gsc = (gcfp)scores;
    const unsigned base = (unsigned)(b * VOCAB);
    constexpr unsigned ROWW = (unsigned)(BATCH * VOCAB);

    int tok[4];
#pragma unroll
    for (int c = 0; c < 4; ++c) {
        const int col = t * 4 + c;
        tok[c] = targets[b * TARGET_LEN + (col < TARGET_LEN ? col : TARGET_LEN - 1)];
    }

    float prev[4];
#pragma unroll
    for (int c = 0; c < 4; ++c) prev[c] = NEGF;
    if (t == 0) prev[0] = gsc[base + (unsigned)tok[0]] * L2E;

    elds[1][t] = gsc[1u * ROWW + base + (unsigned)t];
    elds[2][t] = gsc[2u * ROWW + base + (unsigned)t];
    if (lane == 63) bnd[0][w] = NEGF;

    float g[4];
    g[3] = gsc[3u * ROWW + base + (unsigned)t];
    g[0] = gsc[4u * ROWW + base + (unsigned)t];
    g[1] = gsc[5u * ROWW + base + (unsigned)t];
    g[2] = gsc[6u * ROWW + base + (unsigned)t];

    const int fth = (tlen - 1) >> 2;
    const int fcc = (tlen - 1) & 3;

#define STEP(K)                                                                    \
    {                                                                              \
        const int i = ib + (K);                                                    \
        if (i < N_FRAMES) {                                                        \
            asm volatile("s_waitcnt lgkmcnt(0)" ::: "memory");                     \
            __builtin_amdgcn_s_barrier();                                          \
            asm volatile("" ::: "memory");                                         \
            const int sl = i & 3;                                                  \
            const float ec0 = elds[sl][tok[0]];                                    \
            const float ec1 = elds[sl][tok[1]];                                    \
            const float ec2 = elds[sl][tok[2]];                                    \
            const float ec3 = elds[sl][tok[3]];                                    \
            const float fromLds = (w > 0) ? bnd[(i - 1) & 1][w - 1] : NEGF;        \
            if (i + 2 < N_FRAMES) elds[(i + 2) & 3][t] = g[((K) + 3) & 3];         \
            if (i + 6 < N_FRAMES)                                                  \
                g[((K) + 3) & 3] = gsc[(unsigned)(i + 6) * ROWW + base + (unsigned)t]; \
            const float sh   = __shfl_up(prev[3], 1);                              \
            const float left = (lane == 0) ? fromLds : sh;                         \
            float cur0, cur1, cur2, cur3;                                          \
            CELL(cur0, left,    prev[0], ec0);                                     \
            CELL(cur1, prev[0], prev[1], ec1);                                     \
            CELL(cur2, prev[1], prev[2], ec2);                                     \
            CELL(cur3, prev[2], prev[3], ec3);                                     \
            if (lane == 63) bnd[i & 1][w] = cur3;                                  \
            if (i == inlen - 1 && t == fth) {                                      \
                const float v = (fcc == 0) ? cur0 : (fcc == 1) ? cur1              \
                              : (fcc == 2) ? cur2 : cur3;                          \
                ws_final[b] = v * LN2;                                             \
            }                                                                      \
            prev[0] = cur0; prev[1] = cur1; prev[2] = cur2; prev[3] = cur3;        \
        }                                                                          \
    }

    for (int ib = 1; ib < N_FRAMES; ib += 4) {
        STEP(0) STEP(1) STEP(2) STEP(3)
    }
#undef STEP
}

extern "C" void kernel_launch(void* const* d_in, const int* in_sizes, int n_in,
                              void* d_out, int out_size, void* d_ws, size_t ws_size,
                              hipStream_t stream)
{
    const float* scores  = (const float*)d_in[0];
    const int*   targets = (const int*)  d_in[1];
    const int*   in_len  = (const int*)  d_in[2];
    const int*   tg_len  = (const int*)  d_in[3];
    float*       out     = (float*)d_out;
    float*       ws_fin  = (float*)d_ws;                     // [0,256): per-batch finals

    const size_t cnt_off  = 2048;                            // 4B counter
    const size_t wsA_off  = 4096;
    const size_t wsB_off  = wsA_off + (size_t)BATCH * 1024 * sizeof(float);   // +128KB
    const size_t emit_off = wsB_off + (size_t)BATCH * 1024 * sizeof(float);   // +128KB
    const size_t emit_bytes = (size_t)BATCH * N_FRAMES * 1024 * sizeof(__half);
    const size_t need = emit_off + emit_bytes;

    if (ws_size >= need) {
        __half*   emit = (__half*)((char*)d_ws + emit_off);
        float*    wsA  = (float*)((char*)d_ws + wsA_off);
        float*    wsB  = (float*)((char*)d_ws + wsB_off);
        unsigned* cnt  = (unsigned*)((char*)d_ws + cnt_off);
        hipMemsetAsync(cnt, 0, sizeof(unsigned), stream);    // graph-capture-safe
        dim3 ggrid(N_FRAMES, BATCH);
        gather_emit<<<ggrid, 256, 0, stream>>>(scores, targets, in_len, emit);
        align_dp_fb<<<dim3(BATCH, 2), 512, 0, stream>>>(emit, in_len, tg_len, wsA, wsB);
        lse_combine<<<BATCH, 512, 0, stream>>>(wsA, wsB, ws_fin, cnt, out);
    } else {
        align_dp4<<<BATCH, 256, 0, stream>>>(scores, targets, in_len, tg_len, ws_fin);
        reduce_kernel<<<1, 64, 0, stream>>>(ws_fin, out);
    }
}

// Round 21
// 187.728 us; speedup vs baseline: 1.2612x; 1.0404x over previous
//
#include <hip/hip_runtime.h>
#include <hip/hip_fp16.h>

// Problem constants (from reference)
constexpr int N_FRAMES   = 2000;
constexpr int BATCH      = 32;
constexpr int TARGET_LEN = 1000;
constexpr int VOCAB      = 256;
constexpr int CH         = 16;       // rows per chunk/phase (R13-proven)
constexpr int NW         = 8;        // waves per block (2 per SIMD)
#define NEGF (-1e30f)

// addrspace(1) pointers => guaranteed global_load (vmcnt only, never flat).
typedef __attribute__((address_space(1))) const float* gcfp;
typedef __attribute__((address_space(1))) const unsigned* gcu32;

typedef float f32x2 __attribute__((ext_vector_type(2)));

#define H2F(us) __half2float(__ushort_as_half((unsigned short)(us)))

// Cross-lane shift-by-1 via DPP (pure VALU, NO LDS pipe / lgkmcnt).
//   wf_sr1 (0x138): lane n <- lane n-1  == shfl_up(x,1)
//   wf_sl1 (0x130): lane n <- lane n+1  == shfl_down(x,1)
// (verified R16, absmax 0.0)
#if __has_builtin(__builtin_amdgcn_update_dpp)
__device__ __forceinline__ float lane_up1(float x) {
    return __int_as_float(__builtin_amdgcn_update_dpp(
        0, __float_as_int(x), 0x138, 0xf, 0xf, false));
}
__device__ __forceinline__ float lane_dn1(float x) {
    return __int_as_float(__builtin_amdgcn_update_dpp(
        0, __float_as_int(x), 0x130, 0xf, 0xf, false));
}
#else
__device__ __forceinline__ float lane_up1(float x) { return __shfl_up(x, 1); }
__device__ __forceinline__ float lane_dn1(float x) { return __shfl_down(x, 1); }
#endif

// log2(1+x) on [0,1], degree-5 minimax (validated R9-R16, absmax 0.0),
// Estrin form: dependency depth 4.
__device__ __forceinline__ f32x2 l21p(f32x2 x) {
    const f32x2 x2 = x * x;
    const f32x2 x4 = x2 * x2;
    f32x2 lo = x * 1.44196727f;
    const f32x2 Bq = x * 0.4176245f  - 0.7096745f;
    const f32x2 Cq = x * 0.0464048f  - 0.1963066f;
    lo = x2 * Bq + lo;
    return x4 * Cq + lo;
}
// c = E + max(A,U) + log2(1+2^-|A-U|)
__device__ __forceinline__ f32x2 lse_e(f32x2 A, f32x2 U, f32x2 E) {
    f32x2 m; m.x = fmaxf(A.x, U.x); m.y = fmaxf(A.y, U.y);
    const f32x2 d = A - U;
    f32x2 x;
    x.x = __builtin_amdgcn_exp2f(-fabsf(d.x));
    x.y = __builtin_amdgcn_exp2f(-fabsf(d.y));
    const f32x2 s = E + m;
    return l21p(x) + s;
}
// c = max(A,U) + log2(1+2^-|A-U|)
__device__ __forceinline__ f32x2 lse_core(f32x2 A, f32x2 U) {
    f32x2 m; m.x = fmaxf(A.x, U.x); m.y = fmaxf(A.y, U.y);
    const f32x2 d = A - U;
    f32x2 x;
    x.x = __builtin_amdgcn_exp2f(-fabsf(d.x));
    x.y = __builtin_amdgcn_exp2f(-fabsf(d.y));
    return l21p(x) + m;
}

// ---------------- Phase 1: massively parallel emit gather ----------------
// emit[b][i][col] = fp16( scores[i,b,tgt[b][min(col,999)]] * log2(e) )
// Rows i >= in_len[b] are never read by the DP -> skip (~25% traffic).
__global__ __launch_bounds__(256)
void gather_emit(const float* __restrict__ scores,
                 const int*   __restrict__ targets,
                 const int*   __restrict__ in_len,
                 __half*      __restrict__ emit)
{
    constexpr float L2E = 1.44269504088896340736f;
    const int i = blockIdx.x;
    const int b = blockIdx.y;
    if (i >= in_len[b]) return;
    const int t = threadIdx.x;

    const gcfp gsc = (gcfp)scores;
    const unsigned sbase = (unsigned)(i * BATCH * VOCAB + b * VOCAB);

    int tk0, tk1, tk2, tk3;
    if (t < TARGET_LEN / 4) {
        const int4 tk = *(const int4*)&targets[b * TARGET_LEN + 4 * t];
        tk0 = tk.x; tk1 = tk.y; tk2 = tk.z; tk3 = tk.w;
    } else {
        tk0 = tk1 = tk2 = tk3 = targets[b * TARGET_LEN + TARGET_LEN - 1];
    }

    const float e0 = gsc[sbase + (unsigned)tk0] * L2E;
    const float e1 = gsc[sbase + (unsigned)tk1] * L2E;
    const float e2 = gsc[sbase + (unsigned)tk2] * L2E;
    const float e3 = gsc[sbase + (unsigned)tk3] * L2E;

    const unsigned long long h0 = __half_as_ushort(__float2half_rn(e0));
    const unsigned long long h1 = __half_as_ushort(__float2half_rn(e1));
    const unsigned long long h2 = __half_as_ushort(__float2half_rn(e2));
    const unsigned long long h3 = __half_as_ushort(__float2half_rn(e3));

    const unsigned long long u = h0 | (h1 << 16) | (h2 << 32) | (h3 << 48);
    *(unsigned long long*)(emit + (((size_t)(b * N_FRAMES + i)) << 10) + 4 * t) = u;
}

// ---------------- Phase 2: forward+backward halves, one launch ----------------
// grid (BATCH, 2): y==0 forward rows 1..m -> wsA = alpha[m,*];
//                  y==1 backward rows inlen-2..m -> wsB = beta[m,*].
// R13/R16-verified skeleton (CH=16): 8 waves x 2 cols/lane, deterministic
// skewed chunks, branchless folded bodies, pk cells, DPP cross-lane, raw
// s_barrier + lgkm-only drain per phase. (Byte-identical to R16's DP.)
__global__ __launch_bounds__(512)
void align_dp_fb(const __half* __restrict__ emit,   // [B][N][1024] premult L2E
                 const int*    __restrict__ in_len,
                 const int*    __restrict__ tg_len,
                 float*        __restrict__ wsA,    // [B][1024]
                 float*        __restrict__ wsB)    // [B][1024]
{
    const int b    = blockIdx.x;
    const int t    = threadIdx.x;            // 0..511
    const int lane = t & 63;
    const int w    = t >> 6;                 // 0..7

    __shared__ float bpub[NW - 1][2][CH];

    const int inlen = in_len[b];
    const int m     = (inlen - 1) >> 1;      // cut row (499..999)

    const gcu32 gem = (gcu32)(emit + (((size_t)b * N_FRAMES) << 10));

    if (blockIdx.y == 0) {
        // ================= FORWARD: alpha rows 1..m =================
        const int NCHf = (m + CH - 1) / CH;
        float p0 = NEGF, p1 = NEGF;
        if (t == 0) p0 = H2F(gem[0] & 0xffffu);

        unsigned ring[CH];
#pragma unroll
        for (int r = 0; r < CH; ++r) ring[r] = gem[(unsigned)((1 + r) << 9) + (unsigned)t];

        float shprev = NEGF, carry = NEGF;
        f32x2* wsA2 = (f32x2*)(wsA + (b << 10));

        // all rows/refills in-range (i <= m+15, +16 <= inlen-1): no guards
#define FROWX(r, SNAPF, Bv, Ov)                                                 \
        {                                                                       \
            const int i = i0 + (r);                                             \
            const unsigned u = ring[r];                                         \
            ring[r] = gem[(unsigned)((i + CH) << 9) + (unsigned)t];             \
            f32x2 E; E.x = H2F(u & 0xffffu); E.y = H2F(u >> 16);                \
            f32x2 A; A.x = (lane == 0) ? (Bv) : shprev; A.y = p0;               \
            f32x2 U; U.x = p0; U.y = p1;                                        \
            const f32x2 c = lse_e(A, U, E);                                     \
            shprev = lane_up1(c.y);                                             \
            (Ov) = c.y;                                                         \
            if (SNAPF) { if (i == m) wsA2[t] = c; }                             \
            p0 = c.x; p1 = c.y;                                                 \
        }

#define FBODY(SNAPF)                                                            \
        {                                                                       \
            FROWX(0,  SNAPF, B0,  o0)  FROWX(1,  SNAPF, B1,  o1)                \
            FROWX(2,  SNAPF, B2,  o2)  FROWX(3,  SNAPF, B3,  o3)                \
            FROWX(4,  SNAPF, B4,  o4)  FROWX(5,  SNAPF, B5,  o5)                \
            FROWX(6,  SNAPF, B6,  o6)  FROWX(7,  SNAPF, B7,  o7)                \
            FROWX(8,  SNAPF, B8,  o8)  FROWX(9,  SNAPF, B9,  o9)                \
            FROWX(10, SNAPF, B10, o10) FROWX(11, SNAPF, B11, o11)               \
            FROWX(12, SNAPF, B12, o12) FROWX(13, SNAPF, B13, o13)               \
            FROWX(14, SNAPF, B14, o14) FROWX(15, SNAPF, B15, o15)               \
        }

        const int NPHf = NCHf + NW - 1;
        for (int p = 0; p < NPHf; ++p) {
            const int q = p - w;
            if (q >= 0 && q < NCHf) {
                const int i0  = 1 + q * CH;
                const int par = q & 1;

                float B0 = NEGF, B1 = NEGF, B2 = NEGF, B3 = NEGF,
                      B4 = NEGF, B5 = NEGF, B6 = NEGF, B7 = NEGF,
                      B8 = NEGF, B9 = NEGF, B10 = NEGF, B11 = NEGF,
                      B12 = NEGF, B13 = NEGF, B14 = NEGF, B15 = NEGF;
                if (w > 0) {
                    const float* vp = &bpub[w - 1][par][0];
                    B0 = carry;
                    B1  = vp[0];  B2  = vp[1];  B3  = vp[2];  B4  = vp[3];
                    B5  = vp[4];  B6  = vp[5];  B7  = vp[6];  B8  = vp[7];
                    B9  = vp[8];  B10 = vp[9];  B11 = vp[10]; B12 = vp[11];
                    B13 = vp[12]; B14 = vp[13]; B15 = vp[14];
                    carry = vp[15];
                }

                float o0, o1, o2, o3, o4, o5, o6, o7,
                      o8, o9, o10, o11, o12, o13, o14, o15;

                if (q == NCHf - 1) FBODY(true) else FBODY(false)

                if (w < NW - 1 && lane == 63) {
                    float* dp = &bpub[w][par][0];
                    dp[0]  = o0;  dp[1]  = o1;  dp[2]  = o2;  dp[3]  = o3;
                    dp[4]  = o4;  dp[5]  = o5;  dp[6]  = o6;  dp[7]  = o7;
                    dp[8]  = o8;  dp[9]  = o9;  dp[10] = o10; dp[11] = o11;
                    dp[12] = o12; dp[13] = o13; dp[14] = o14; dp[15] = o15;
                }
            }
            asm volatile("s_waitcnt lgkmcnt(0)" ::: "memory");
            __builtin_amdgcn_s_barrier();
            asm volatile("" ::: "memory");
        }
#undef FBODY
#undef FROWX
    } else {
        // ================= BACKWARD: beta rows inlen-2..m =================
        const int tlen   = tg_len[b];
        const int istart = inlen - 1;
        const int NCHb   = (istart - m + CH - 1) / CH;
        const int fth    = (tlen - 1) >> 1;
        const int fcc    = (tlen - 1) & 1;

        float p0 = NEGF, p1 = NEGF;
        if (t == fth) { if (fcc == 0) p0 = 0.0f; else p1 = 0.0f; }

        unsigned ring[CH];
#pragma unroll
        for (int r = 0; r < CH; ++r)
            ring[r] = gem[(unsigned)((istart - r) << 9) + (unsigned)t];

        f32x2* wsB2 = (f32x2*)(wsB + (b << 10));

        // beta[i,j] = LSE(x_j, x_{j+1}), x_j = e[i+1,j] + beta[i+1,j].
        // x at row start -> DPP shift down; publish x.x (lane0). Junk rows
        // below m (tail) compute after snapshot; refills >= m-2CH+2 >= 0.
#define BROWX(r, SNAPF, Bv, Ov)                                                 \
        {                                                                       \
            const int i = i0 - (r);                                             \
            const unsigned u = ring[r];                                         \
            ring[r] = gem[(unsigned)((i + 1 - CH) << 9) + (unsigned)t];         \
            f32x2 E; E.x = H2F(u & 0xffffu); E.y = H2F(u >> 16);                \
            f32x2 P; P.x = p0; P.y = p1;                                        \
            const f32x2 x = E + P;                                              \
            const float sh = lane_dn1(x.x);                                     \
            (Ov) = x.x;                                                         \
            const float xR = (lane == 63) ? (Bv) : sh;                          \
            f32x2 A; A.x = x.x; A.y = x.y;                                      \
            f32x2 U; U.x = x.y; U.y = xR;                                       \
            const f32x2 c = lse_core(A, U);                                     \
            if (SNAPF) { if (i == m) wsB2[t] = c; }                             \
            p0 = c.x; p1 = c.y;                                                 \
        }

#define BBODY(SNAPF)                                                            \
        {                                                                       \
            BROWX(0,  SNAPF, B0,  o0)  BROWX(1,  SNAPF, B1,  o1)                \
            BROWX(2,  SNAPF, B2,  o2)  BROWX(3,  SNAPF, B3,  o3)                \
            BROWX(4,  SNAPF, B4,  o4)  BROWX(5,  SNAPF, B5,  o5)                \
            BROWX(6,  SNAPF, B6,  o6)  BROWX(7,  SNAPF, B7,  o7)                \
            BROWX(8,  SNAPF, B8,  o8)  BROWX(9,  SNAPF, B9,  o9)                \
            BROWX(10, SNAPF, B10, o10) BROWX(11, SNAPF, B11, o11)               \
            BROWX(12, SNAPF, B12, o12) BROWX(13, SNAPF, B13, o13)               \
            BROWX(14, SNAPF, B14, o14) BROWX(15, SNAPF, B15, o15)               \
        }

        const int NPHb = NCHb + NW - 1;
        for (int p = 0; p < NPHb; ++p) {
            const int q = p - (NW - 1 - w);   // wave 7 leads (info flows right->left)
            if (q >= 0 && q < NCHb) {
                const int i0  = istart - 1 - q * CH;
                const int par = q & 1;

                float B0 = NEGF, B1 = NEGF, B2 = NEGF, B3 = NEGF,
                      B4 = NEGF, B5 = NEGF, B6 = NEGF, B7 = NEGF,
                      B8 = NEGF, B9 = NEGF, B10 = NEGF, B11 = NEGF,
                      B12 = NEGF, B13 = NEGF, B14 = NEGF, B15 = NEGF;
                if (w < NW - 1) {   // consume right wave's lane-0 x values
                    const float* vp = &bpub[w][par][0];
                    B0  = vp[0];  B1  = vp[1];  B2  = vp[2];  B3  = vp[3];
                    B4  = vp[4];  B5  = vp[5];  B6  = vp[6];  B7  = vp[7];
                    B8  = vp[8];  B9  = vp[9];  B10 = vp[10]; B11 = vp[11];
                    B12 = vp[12]; B13 = vp[13]; B14 = vp[14]; B15 = vp[15];
                }

                float o0, o1, o2, o3, o4, o5, o6, o7,
                      o8, o9, o10, o11, o12, o13, o14, o15;

                if (q == NCHb - 1) BBODY(true) else BBODY(false)

                if (w > 0 && lane == 0) {     // publish for left wave
                    float* dp = &bpub[w - 1][par][0];
                    dp[0]  = o0;  dp[1]  = o1;  dp[2]  = o2;  dp[3]  = o3;
                    dp[4]  = o4;  dp[5]  = o5;  dp[6]  = o6;  dp[7]  = o7;
                    dp[8]  = o8;  dp[9]  = o9;  dp[10] = o10; dp[11] = o11;
                    dp[12] = o12; dp[13] = o13; dp[14] = o14; dp[15] = o15;
                }
            }
            asm volatile("s_waitcnt lgkmcnt(0)" ::: "memory");
            __builtin_amdgcn_s_barrier();
            asm volatile("" ::: "memory");
        }
#undef BBODY
#undef BROWX
    }
}

// ---------------- Phase 3: LSE join over the cut row ----------------
// ws_final[b] = ln2 * log2 sum_j 2^( alphaB[m,j] + betaB[m,j] )
__global__ __launch_bounds__(512)
void lse_combine(const float* __restrict__ wsA, const float* __restrict__ wsB,
                 float* __restrict__ ws_final)
{
    constexpr float LN2 = 0.69314718055994530942f;
    const int b = blockIdx.x, t = threadIdx.x, lane = t & 63, w = t >> 6;
    __shared__ float red[8];

    const float* A  = wsA + (b << 10);
    const float* Bv = wsB + (b << 10);
    const float v0 = A[2 * t]     + Bv[2 * t];
    const float v1 = A[2 * t + 1] + Bv[2 * t + 1];

    float mx = fmaxf(v0, v1);
#pragma unroll
    for (int off = 1; off < 64; off <<= 1) mx = fmaxf(mx, __shfl_xor(mx, off));
    if (lane == 0) red[w] = mx;
    __syncthreads();
    float gm = red[0];
#pragma unroll
    for (int k = 1; k < 8; ++k) gm = fmaxf(gm, red[k]);

    float s = __builtin_amdgcn_exp2f(v0 - gm) + __builtin_amdgcn_exp2f(v1 - gm);
#pragma unroll
    for (int off = 1; off < 64; off <<= 1) s += __shfl_xor(s, off);
    __syncthreads();
    if (lane == 0) red[w] = s;
    __syncthreads();
    if (t == 0) {
        float tot = red[0];
#pragma unroll
        for (int k = 1; k < 8; ++k) tot += red[k];
        ws_final[b] = (gm + __builtin_amdgcn_logf(tot)) * LN2;
    }
}

// Final scalar: out = -sum(ws_final)/BATCH. Unconditional write.
__global__ void reduce_kernel(const float* __restrict__ ws_final, float* __restrict__ out)
{
    if (threadIdx.x == 0 && blockIdx.x == 0) {
        float s = 0.0f;
        for (int b = 0; b < BATCH; ++b) s += ws_final[b];
        out[0] = -s / (float)BATCH;
    }
}

// ---------------- Fallback (verified R3 kernel) if ws too small ----------------
#define CELL(dst, A, U, E)                                            \
    {                                                                 \
        const float m_ = fmaxf((A), (U));                             \
        const float d_ = (A) - (U);                                   \
        const float p_ = __builtin_amdgcn_exp2f(-fabsf(d_));          \
        const float l_ = __builtin_amdgcn_logf(1.0f + p_);            \
        (dst) = fmaf((E), L2E, m_ + l_);                              \
    }

__global__ __launch_bounds__(256)
void align_dp4(const float* __restrict__ scores,
               const int*   __restrict__ targets,
               const int*   __restrict__ in_len,
               const int*   __restrict__ tg_len,
               float*       __restrict__ ws_final)
{
    constexpr float L2E = 1.44269504088896340736f;
    constexpr float LN2 = 0.69314718055994530942f;

    const int b    = blockIdx.x;
    const int t    = threadIdx.x;
    const int lane = t & 63;
    const int w    = t >> 6;

    __shared__ float elds[4][VOCAB];
    __shared__ float bnd[2][8];

    const int inlen = in_len[b];
    const int tlen  = tg_len[b];

    const gcfp gsc = (gcfp)scores;
    const unsigned base = (unsigned)(b * VOCAB);
    constexpr unsigned ROWW = (unsigned)(BATCH * VOCAB);

    int tok[4];
#pragma unroll
    for (int c = 0; c < 4; ++c) {
        const int col = t * 4 + c;
        tok[c] = targets[b * TARGET_LEN + (col < TARGET_LEN ? col : TARGET_LEN - 1)];
    }

    float prev[4];
#pragma unroll
    for (int c = 0; c < 4; ++c) prev[c] = NEGF;
    if (t == 0) prev[0] = gsc[base + (unsigned)tok[0]] * L2E;

    elds[1][t] = gsc[1u * ROWW + base + (unsigned)t];
    elds[2][t] = gsc[2u * ROWW + base + (unsigned)t];
    if (lane == 63) bnd[0][w] = NEGF;

    float g[4];
    g[3] = gsc[3u * ROWW + base + (unsigned)t];
    g[0] = gsc[4u * ROWW + base + (unsigned)t];
    g[1] = gsc[5u * ROWW + base + (unsigned)t];
    g[2] = gsc[6u * ROWW + base + (unsigned)t];

    const int fth = (tlen - 1) >> 2;
    const int fcc = (tlen - 1) & 3;

#define STEP(K)                                                                    \
    {                                                                              \
        const int i = ib + (K);                                                    \
        if (i < N_FRAMES) {                                                        \
            asm volatile("s_waitcnt lgkmcnt(0)" ::: "memory");                     \
            __builtin_amdgcn_s_barrier();                                          \
            asm volatile("" ::: "memory");                                         \
            const int sl = i & 3;                                                  \
            const float ec0 = elds[sl][tok[0]];                                    \
            const float ec1 = elds[sl][tok[1]];                                    \
            const float ec2 = elds[sl][tok[2]];                                    \
            const float ec3 = elds[sl][tok[3]];                                    \
            const float fromLds = (w > 0) ? bnd[(i - 1) & 1][w - 1] : NEGF;        \
            if (i + 2 < N_FRAMES) elds[(i + 2) & 3][t] = g[((K) + 3) & 3];         \
            if (i + 6 < N_FRAMES)                                                  \
                g[((K) + 3) & 3] = gsc[(unsigned)(i + 6) * ROWW + base + (unsigned)t]; \
            const float sh   = __shfl_up(prev[3], 1);                              \
            const float left = (lane == 0) ? fromLds : sh;                         \
            float cur0, cur1, cur2, cur3;                                          \
            CELL(cur0, left,    prev[0], ec0);                                     \
            CELL(cur1, prev[0], prev[1], ec1);                                     \
            CELL(cur2, prev[1], prev[2], ec2);                                     \
            CELL(cur3, prev[2], prev[3], ec3);                                     \
            if (lane == 63) bnd[i & 1][w] = cur3;                                  \
            if (i == inlen - 1 && t == fth) {                                      \
                const float v = (fcc == 0) ? cur0 : (fcc == 1) ? cur1              \
                              : (fcc == 2) ? cur2 : cur3;                          \
                ws_final[b] = v * LN2;                                             \
            }                                                                      \
            prev[0] = cur0; prev[1] = cur1; prev[2] = cur2; prev[3] = cur3;        \
        }                                                                          \
    }

    for (int ib = 1; ib < N_FRAMES; ib += 4) {
        STEP(0) STEP(1) STEP(2) STEP(3)
    }
#undef STEP
}

extern "C" void kernel_launch(void* const* d_in, const int* in_sizes, int n_in,
                              void* d_out, int out_size, void* d_ws, size_t ws_size,
                              hipStream_t stream)
{
    const float* scores  = (const float*)d_in[0];
    const int*   targets = (const int*)  d_in[1];
    const int*   in_len  = (const int*)  d_in[2];
    const int*   tg_len  = (const int*)  d_in[3];
    float*       out     = (float*)d_out;
    float*       ws_fin  = (float*)d_ws;                     // [0,256): per-batch finals

    const size_t emit_bytes = (size_t)BATCH * N_FRAMES * 1024 * sizeof(__half);
    const size_t wsA_off  = 4096;
    const size_t wsB_off  = wsA_off + (size_t)BATCH * 1024 * sizeof(float);   // +128KB
    const size_t emit_off = wsB_off + (size_t)BATCH * 1024 * sizeof(float);   // +128KB
    const size_t need = emit_off + emit_bytes;

    if (ws_size >= need) {
        __half* emit = (__half*)((char*)d_ws + emit_off);
        float*  wsA  = (float*)((char*)d_ws + wsA_off);
        float*  wsB  = (float*)((char*)d_ws + wsB_off);
        dim3 ggrid(N_FRAMES, BATCH);
        gather_emit<<<ggrid, 256, 0, stream>>>(scores, targets, in_len, emit);
        align_dp_fb<<<dim3(BATCH, 2), 512, 0, stream>>>(emit, in_len, tg_len, wsA, wsB);
        lse_combine<<<BATCH, 512, 0, stream>>>(wsA, wsB, ws_fin);
    } else {
        align_dp4<<<BATCH, 256, 0, stream>>>(scores, targets, in_len, tg_len, ws_fin);
    }
    reduce_kernel<<<1, 64, 0, stream>>>(ws_fin, out);
}

// Round 22
// 163.607 us; speedup vs baseline: 1.4472x; 1.1474x over previous
//
#include <hip/hip_runtime.h>
#include <hip/hip_fp16.h>

// Problem constants (from reference)
constexpr int N_FRAMES   = 2000;
constexpr int BATCH      = 32;
constexpr int TARGET_LEN = 1000;
constexpr int VOCAB      = 256;
constexpr int CH         = 16;       // rows per chunk/phase (R13-proven)
constexpr int NW         = 8;        // waves per block (2 per SIMD)
constexpr int RPB        = 8;        // gather: rows per block
#define NEGF (-1e30f)

// addrspace(1) pointers => guaranteed global_load (vmcnt only, never flat).
typedef __attribute__((address_space(1))) const float* gcfp;
typedef __attribute__((address_space(1))) const unsigned* gcu32;

typedef float f32x2 __attribute__((ext_vector_type(2)));

#define H2F(us) __half2float(__ushort_as_half((unsigned short)(us)))

// Cross-lane shift-by-1 via DPP (pure VALU, NO LDS pipe / lgkmcnt).
//   wf_sr1 (0x138): lane n <- lane n-1  == shfl_up(x,1)
//   wf_sl1 (0x130): lane n <- lane n+1  == shfl_down(x,1)
// (verified R16, absmax 0.0)
#if __has_builtin(__builtin_amdgcn_update_dpp)
__device__ __forceinline__ float lane_up1(float x) {
    return __int_as_float(__builtin_amdgcn_update_dpp(
        0, __float_as_int(x), 0x138, 0xf, 0xf, false));
}
__device__ __forceinline__ float lane_dn1(float x) {
    return __int_as_float(__builtin_amdgcn_update_dpp(
        0, __float_as_int(x), 0x130, 0xf, 0xf, false));
}
#else
__device__ __forceinline__ float lane_up1(float x) { return __shfl_up(x, 1); }
__device__ __forceinline__ float lane_dn1(float x) { return __shfl_down(x, 1); }
#endif

// log2(1+x) on [0,1], degree-5 minimax (validated R9-R16, absmax 0.0),
// Estrin form: dependency depth 4.
__device__ __forceinline__ f32x2 l21p(f32x2 x) {
    const f32x2 x2 = x * x;
    const f32x2 x4 = x2 * x2;
    f32x2 lo = x * 1.44196727f;
    const f32x2 Bq = x * 0.4176245f  - 0.7096745f;
    const f32x2 Cq = x * 0.0464048f  - 0.1963066f;
    lo = x2 * Bq + lo;
    return x4 * Cq + lo;
}
// c = E + max(A,U) + log2(1+2^-|A-U|)
__device__ __forceinline__ f32x2 lse_e(f32x2 A, f32x2 U, f32x2 E) {
    f32x2 m; m.x = fmaxf(A.x, U.x); m.y = fmaxf(A.y, U.y);
    const f32x2 d = A - U;
    f32x2 x;
    x.x = __builtin_amdgcn_exp2f(-fabsf(d.x));
    x.y = __builtin_amdgcn_exp2f(-fabsf(d.y));
    const f32x2 s = E + m;
    return l21p(x) + s;
}
// c = max(A,U) + log2(1+2^-|A-U|)
__device__ __forceinline__ f32x2 lse_core(f32x2 A, f32x2 U) {
    f32x2 m; m.x = fmaxf(A.x, U.x); m.y = fmaxf(A.y, U.y);
    const f32x2 d = A - U;
    f32x2 x;
    x.x = __builtin_amdgcn_exp2f(-fabsf(d.x));
    x.y = __builtin_amdgcn_exp2f(-fabsf(d.y));
    return l21p(x) + m;
}

// ---------------- Phase 1: emit gather, 8 rows/block + LDS staging ----------
// emit[b][i][col] = fp16( scores[i,b,tgt[b][min(col,999)]] * log2(e) )
// Each block stages 8 coalesced vocab rows (L2E folded at staging), loads the
// token slice ONCE, then gathers from LDS. Rows i >= in_len[b] skipped.
__global__ __launch_bounds__(256)
void gather_emit3(const float* __restrict__ scores,
                  const int*   __restrict__ targets,
                  const int*   __restrict__ in_len,
                  __half*      __restrict__ emit)
{
    constexpr float L2E = 1.44269504088896340736f;
    const int b     = blockIdx.y;
    const int i0    = blockIdx.x * RPB;
    const int inlen = in_len[b];
    if (i0 >= inlen) return;
    const int t = threadIdx.x;

    __shared__ float sl[RPB][VOCAB];   // 8 KB

    const gcfp gsc = (gcfp)scores;

    // coalesced staging: one 1KB row per r (all-thread-uniform row predicate)
#pragma unroll
    for (int r = 0; r < RPB; ++r) {
        const int i = i0 + r;
        if (i < inlen)
            sl[r][t] = gsc[(unsigned)((i * BATCH + b) * VOCAB) + (unsigned)t] * L2E;
    }

    // tokens loaded once per block (8x amortized vs per-row blocks)
    int tk0, tk1, tk2, tk3;
    if (t < TARGET_LEN / 4) {
        const int4 tk = *(const int4*)&targets[b * TARGET_LEN + 4 * t];
        tk0 = tk.x; tk1 = tk.y; tk2 = tk.z; tk3 = tk.w;
    } else {
        tk0 = tk1 = tk2 = tk3 = targets[b * TARGET_LEN + TARGET_LEN - 1];
    }

    __syncthreads();

#pragma unroll
    for (int r = 0; r < RPB; ++r) {
        const int i = i0 + r;
        if (i < inlen) {
            const unsigned long long h0 = __half_as_ushort(__float2half_rn(sl[r][tk0]));
            const unsigned long long h1 = __half_as_ushort(__float2half_rn(sl[r][tk1]));
            const unsigned long long h2 = __half_as_ushort(__float2half_rn(sl[r][tk2]));
            const unsigned long long h3 = __half_as_ushort(__float2half_rn(sl[r][tk3]));
            const unsigned long long u = h0 | (h1 << 16) | (h2 << 32) | (h3 << 48);
            *(unsigned long long*)(emit + (((size_t)(b * N_FRAMES + i)) << 10) + 4 * t) = u;
        }
    }
}

// ---------------- Phase 2: forward+backward halves, one launch ----------------
// grid (BATCH, 2): y==0 forward rows 1..m -> wsA = alpha[m,*];
//                  y==1 backward rows inlen-2..m -> wsB = beta[m,*].
// R13/R16-verified skeleton (CH=16): 8 waves x 2 cols/lane, deterministic
// skewed chunks, branchless folded bodies, pk cells, DPP cross-lane, raw
// s_barrier + lgkm-only drain per phase. (Byte-identical to R16's DP.)
__global__ __launch_bounds__(512)
void align_dp_fb(const __half* __restrict__ emit,   // [B][N][1024] premult L2E
                 const int*    __restrict__ in_len,
                 const int*    __restrict__ tg_len,
                 float*        __restrict__ wsA,    // [B][1024]
                 float*        __restrict__ wsB)    // [B][1024]
{
    const int b    = blockIdx.x;
    const int t    = threadIdx.x;            // 0..511
    const int lane = t & 63;
    const int w    = t >> 6;                 // 0..7

    __shared__ float bpub[NW - 1][2][CH];

    const int inlen = in_len[b];
    const int m     = (inlen - 1) >> 1;      // cut row (499..999)

    const gcu32 gem = (gcu32)(emit + (((size_t)b * N_FRAMES) << 10));

    if (blockIdx.y == 0) {
        // ================= FORWARD: alpha rows 1..m =================
        const int NCHf = (m + CH - 1) / CH;
        float p0 = NEGF, p1 = NEGF;
        if (t == 0) p0 = H2F(gem[0] & 0xffffu);

        unsigned ring[CH];
#pragma unroll
        for (int r = 0; r < CH; ++r) ring[r] = gem[(unsigned)((1 + r) << 9) + (unsigned)t];

        float shprev = NEGF, carry = NEGF;
        f32x2* wsA2 = (f32x2*)(wsA + (b << 10));

        // all rows/refills in-range (i <= m+15, +16 <= inlen-1): no guards
#define FROWX(r, SNAPF, Bv, Ov)                                                 \
        {                                                                       \
            const int i = i0 + (r);                                             \
            const unsigned u = ring[r];                                         \
            ring[r] = gem[(unsigned)((i + CH) << 9) + (unsigned)t];             \
            f32x2 E; E.x = H2F(u & 0xffffu); E.y = H2F(u >> 16);                \
            f32x2 A; A.x = (lane == 0) ? (Bv) : shprev; A.y = p0;               \
            f32x2 U; U.x = p0; U.y = p1;                                        \
            const f32x2 c = lse_e(A, U, E);                                     \
            shprev = lane_up1(c.y);                                             \
            (Ov) = c.y;                                                         \
            if (SNAPF) { if (i == m) wsA2[t] = c; }                             \
            p0 = c.x; p1 = c.y;                                                 \
        }

#define FBODY(SNAPF)                                                            \
        {                                                                       \
            FROWX(0,  SNAPF, B0,  o0)  FROWX(1,  SNAPF, B1,  o1)                \
            FROWX(2,  SNAPF, B2,  o2)  FROWX(3,  SNAPF, B3,  o3)                \
            FROWX(4,  SNAPF, B4,  o4)  FROWX(5,  SNAPF, B5,  o5)                \
            FROWX(6,  SNAPF, B6,  o6)  FROWX(7,  SNAPF, B7,  o7)                \
            FROWX(8,  SNAPF, B8,  o8)  FROWX(9,  SNAPF, B9,  o9)                \
            FROWX(10, SNAPF, B10, o10) FROWX(11, SNAPF, B11, o11)               \
            FROWX(12, SNAPF, B12, o12) FROWX(13, SNAPF, B13, o13)               \
            FROWX(14, SNAPF, B14, o14) FROWX(15, SNAPF, B15, o15)               \
        }

        const int NPHf = NCHf + NW - 1;
        for (int p = 0; p < NPHf; ++p) {
            const int q = p - w;
            if (q >= 0 && q < NCHf) {
                const int i0  = 1 + q * CH;
                const int par = q & 1;

                float B0 = NEGF, B1 = NEGF, B2 = NEGF, B3 = NEGF,
                      B4 = NEGF, B5 = NEGF, B6 = NEGF, B7 = NEGF,
                      B8 = NEGF, B9 = NEGF, B10 = NEGF, B11 = NEGF,
                      B12 = NEGF, B13 = NEGF, B14 = NEGF, B15 = NEGF;
                if (w > 0) {
                    const float* vp = &bpub[w - 1][par][0];
                    B0 = carry;
                    B1  = vp[0];  B2  = vp[1];  B3  = vp[2];  B4  = vp[3];
                    B5  = vp[4];  B6  = vp[5];  B7  = vp[6];  B8  = vp[7];
                    B9  = vp[8];  B10 = vp[9];  B11 = vp[10]; B12 = vp[11];
                    B13 = vp[12]; B14 = vp[13]; B15 = vp[14];
                    carry = vp[15];
                }

                float o0, o1, o2, o3, o4, o5, o6, o7,
                      o8, o9, o10, o11, o12, o13, o14, o15;

                if (q == NCHf - 1) FBODY(true) else FBODY(false)

                if (w < NW - 1 && lane == 63) {
                    float* dp = &bpub[w][par][0];
                    dp[0]  = o0;  dp[1]  = o1;  dp[2]  = o2;  dp[3]  = o3;
                    dp[4]  = o4;  dp[5]  = o5;  dp[6]  = o6;  dp[7]  = o7;
                    dp[8]  = o8;  dp[9]  = o9;  dp[10] = o10; dp[11] = o11;
                    dp[12] = o12; dp[13] = o13; dp[14] = o14; dp[15] = o15;
                }
            }
            asm volatile("s_waitcnt lgkmcnt(0)" ::: "memory");
            __builtin_amdgcn_s_barrier();
            asm volatile("" ::: "memory");
        }
#undef FBODY
#undef FROWX
    } else {
        // ================= BACKWARD: beta rows inlen-2..m =================
        const int tlen   = tg_len[b];
        const int istart = inlen - 1;
        const int NCHb   = (istart - m + CH - 1) / CH;
        const int fth    = (tlen - 1) >> 1;
        const int fcc    = (tlen - 1) & 1;

        float p0 = NEGF, p1 = NEGF;
        if (t == fth) { if (fcc == 0) p0 = 0.0f; else p1 = 0.0f; }

        unsigned ring[CH];
#pragma unroll
        for (int r = 0; r < CH; ++r)
            ring[r] = gem[(unsigned)((istart - r) << 9) + (unsigned)t];

        f32x2* wsB2 = (f32x2*)(wsB + (b << 10));

        // beta[i,j] = LSE(x_j, x_{j+1}), x_j = e[i+1,j] + beta[i+1,j].
        // x at row start -> DPP shift down; publish x.x (lane0). Junk rows
        // below m (tail) compute after snapshot; refills >= m-2CH+2 >= 0.
#define BROWX(r, SNAPF, Bv, Ov)                                                 \
        {                                                                       \
            const int i = i0 - (r);                                             \
            const unsigned u = ring[r];                                         \
            ring[r] = gem[(unsigned)((i + 1 - CH) << 9) + (unsigned)t];         \
            f32x2 E; E.x = H2F(u & 0xffffu); E.y = H2F(u >> 16);                \
            f32x2 P; P.x = p0; P.y = p1;                                        \
            const f32x2 x = E + P;                                              \
            const float sh = lane_dn1(x.x);                                     \
            (Ov) = x.x;                                                         \
            const float xR = (lane == 63) ? (Bv) : sh;                          \
            f32x2 A; A.x = x.x; A.y = x.y;                                      \
            f32x2 U; U.x = x.y; U.y = xR;                                       \
            const f32x2 c = lse_core(A, U);                                     \
            if (SNAPF) { if (i == m) wsB2[t] = c; }                             \
            p0 = c.x; p1 = c.y;                                                 \
        }

#define BBODY(SNAPF)                                                            \
        {                                                                       \
            BROWX(0,  SNAPF, B0,  o0)  BROWX(1,  SNAPF, B1,  o1)                \
            BROWX(2,  SNAPF, B2,  o2)  BROWX(3,  SNAPF, B3,  o3)                \
            BROWX(4,  SNAPF, B4,  o4)  BROWX(5,  SNAPF, B5,  o5)                \
            BROWX(6,  SNAPF, B6,  o6)  BROWX(7,  SNAPF, B7,  o7)                \
            BROWX(8,  SNAPF, B8,  o8)  BROWX(9,  SNAPF, B9,  o9)                \
            BROWX(10, SNAPF, B10, o10) BROWX(11, SNAPF, B11, o11)               \
            BROWX(12, SNAPF, B12, o12) BROWX(13, SNAPF, B13, o13)               \
            BROWX(14, SNAPF, B14, o14) BROWX(15, SNAPF, B15, o15)               \
        }

        const int NPHb = NCHb + NW - 1;
        for (int p = 0; p < NPHb; ++p) {
            const int q = p - (NW - 1 - w);   // wave 7 leads (info flows right->left)
            if (q >= 0 && q < NCHb) {
                const int i0  = istart - 1 - q * CH;
                const int par = q & 1;

                float B0 = NEGF, B1 = NEGF, B2 = NEGF, B3 = NEGF,
                      B4 = NEGF, B5 = NEGF, B6 = NEGF, B7 = NEGF,
                      B8 = NEGF, B9 = NEGF, B10 = NEGF, B11 = NEGF,
                      B12 = NEGF, B13 = NEGF, B14 = NEGF, B15 = NEGF;
                if (w < NW - 1) {   // consume right wave's lane-0 x values
                    const float* vp = &bpub[w][par][0];
                    B0  = vp[0];  B1  = vp[1];  B2  = vp[2];  B3  = vp[3];
                    B4  = vp[4];  B5  = vp[5];  B6  = vp[6];  B7  = vp[7];
                    B8  = vp[8];  B9  = vp[9];  B10 = vp[10]; B11 = vp[11];
                    B12 = vp[12]; B13 = vp[13]; B14 = vp[14]; B15 = vp[15];
                }

                float o0, o1, o2, o3, o4, o5, o6, o7,
                      o8, o9, o10, o11, o12, o13, o14, o15;

                if (q == NCHb - 1) BBODY(true) else BBODY(false)

                if (w > 0 && lane == 0) {     // publish for left wave
                    float* dp = &bpub[w - 1][par][0];
                    dp[0]  = o0;  dp[1]  = o1;  dp[2]  = o2;  dp[3]  = o3;
                    dp[4]  = o4;  dp[5]  = o5;  dp[6]  = o6;  dp[7]  = o7;
                    dp[8]  = o8;  dp[9]  = o9;  dp[10] = o10; dp[11] = o11;
                    dp[12] = o12; dp[13] = o13; dp[14] = o14; dp[15] = o15;
                }
            }
            asm volatile("s_waitcnt lgkmcnt(0)" ::: "memory");
            __builtin_amdgcn_s_barrier();
            asm volatile("" ::: "memory");
        }
#undef BBODY
#undef BROWX
    }
}

// ---------------- Phase 3: LSE join over the cut row ----------------
// ws_final[b] = ln2 * log2 sum_j 2^( alphaB[m,j] + betaB[m,j] )
__global__ __launch_bounds__(512)
void lse_combine(const float* __restrict__ wsA, const float* __restrict__ wsB,
                 float* __restrict__ ws_final)
{
    constexpr float LN2 = 0.69314718055994530942f;
    const int b = blockIdx.x, t = threadIdx.x, lane = t & 63, w = t >> 6;
    __shared__ float red[8];

    const float* A  = wsA + (b << 10);
    const float* Bv = wsB + (b << 10);
    const float v0 = A[2 * t]     + Bv[2 * t];
    const float v1 = A[2 * t + 1] + Bv[2 * t + 1];

    float mx = fmaxf(v0, v1);
#pragma unroll
    for (int off = 1; off < 64; off <<= 1) mx = fmaxf(mx, __shfl_xor(mx, off));
    if (lane == 0) red[w] = mx;
    __syncthreads();
    float gm = red[0];
#pragma unroll
    for (int k = 1; k < 8; ++k) gm = fmaxf(gm, red[k]);

    float s = __builtin_amdgcn_exp2f(v0 - gm) + __builtin_amdgcn_exp2f(v1 - gm);
#pragma unroll
    for (int off = 1; off < 64; off <<= 1) s += __shfl_xor(s, off);
    __syncthreads();
    if (lane == 0) red[w] = s;
    __syncthreads();
    if (t == 0) {
        float tot = red[0];
#pragma unroll
        for (int k = 1; k < 8; ++k) tot += red[k];
        ws_final[b] = (gm + __builtin_amdgcn_logf(tot)) * LN2;
    }
}

// Final scalar: out = -sum(ws_final)/BATCH. Unconditional write.
__global__ void reduce_kernel(const float* __restrict__ ws_final, float* __restrict__ out)
{
    if (threadIdx.x == 0 && blockIdx.x == 0) {
        float s = 0.0f;
        for (int b = 0; b < BATCH; ++b) s += ws_final[b];
        out[0] = -s / (float)BATCH;
    }
}

// ---------------- Fallback (verified R3 kernel) if ws too small ----------------
#define CELL(dst, A, U, E)                                            \
    {                                                                 \
        const float m_ = fmaxf((A), (U));                             \
        const float d_ = (A) - (U);                                   \
        const float p_ = __builtin_amdgcn_exp2f(-fabsf(d_));          \
        const float l_ = __builtin_amdgcn_logf(1.0f + p_);            \
        (dst) = fmaf((E), L2E, m_ + l_);                              \
    }

__global__ __launch_bounds__(256)
void align_dp4(const float* __restrict__ scores,
               const int*   __restrict__ targets,
               const int*   __restrict__ in_len,
               const int*   __restrict__ tg_len,
               float*       __restrict__ ws_final)
{
    constexpr float L2E = 1.44269504088896340736f;
    constexpr float LN2 = 0.69314718055994530942f;

    const int b    = blockIdx.x;
    const int t    = threadIdx.x;
    const int lane = t & 63;
    const int w    = t >> 6;

    __shared__ float elds[4][VOCAB];
    __shared__ float bnd[2][8];

    const int inlen = in_len[b];
    const int tlen  = tg_len[b];

    const gcfp gsc = (gcfp)scores;
    const unsigned base = (unsigned)(b * VOCAB);
    constexpr unsigned ROWW = (unsigned)(BATCH * VOCAB);

    int tok[4];
#pragma unroll
    for (int c = 0; c < 4; ++c) {
        const int col = t * 4 + c;
        tok[c] = targets[b * TARGET_LEN + (col < TARGET_LEN ? col : TARGET_LEN - 1)];
    }

    float prev[4];
#pragma unroll
    for (int c = 0; c < 4; ++c) prev[c] = NEGF;
    if (t == 0) prev[0] = gsc[base + (unsigned)tok[0]] * L2E;

    elds[1][t] = gsc[1u * ROWW + base + (unsigned)t];
    elds[2][t] = gsc[2u * ROWW + base + (unsigned)t];
    if (lane == 63) bnd[0][w] = NEGF;

    float g[4];
    g[3] = gsc[3u * ROWW + base + (unsigned)t];
    g[0] = gsc[4u * ROWW + base + (unsigned)t];
    g[1] = gsc[5u * ROWW + base + (unsigned)t];
    g[2] = gsc[6u * ROWW + base + (unsigned)t];

    const int fth = (tlen - 1) >> 2;
    const int fcc = (tlen - 1) & 3;

#define STEP(K)                                                                    \
    {                                                                              \
        const int i = ib + (K);                                                    \
        if (i < N_FRAMES) {                                                        \
            asm volatile("s_waitcnt lgkmcnt(0)" ::: "memory");                     \
            __builtin_amdgcn_s_barrier();                                          \
            asm volatile("" ::: "memory");                                         \
            const int sl = i & 3;                                                  \
            const float ec0 = elds[sl][tok[0]];                                    \
            const float ec1 = elds[sl][tok[1]];                                    \
            const float ec2 = elds[sl][tok[2]];                                    \
            const float ec3 = elds[sl][tok[3]];                                    \
            const float fromLds = (w > 0) ? bnd[(i - 1) & 1][w - 1] : NEGF;        \
            if (i + 2 < N_FRAMES) elds[(i + 2) & 3][t] = g[((K) + 3) & 3];         \
            if (i + 6 < N_FRAMES)                                                  \
                g[((K) + 3) & 3] = gsc[(unsigned)(i + 6) * ROWW + base + (unsigned)t]; \
            const float sh   = __shfl_up(prev[3], 1);                              \
            const float left = (lane == 0) ? fromLds : sh;                         \
            float cur0, cur1, cur2, cur3;                                          \
            CELL(cur0, left,    prev[0], ec0);                                     \
            CELL(cur1, prev[0], prev[1], ec1);                                     \
            CELL(cur2, prev[1], prev[2], ec2);                                     \
            CELL(cur3, prev[2], prev[3], ec3);                                     \
            if (lane == 63) bnd[i & 1][w] = cur3;                                  \
            if (i == inlen - 1 && t == fth) {                                      \
                const float v = (fcc == 0) ? cur0 : (fcc == 1) ? cur1              \
                              : (fcc == 2) ? cur2 : cur3;                          \
                ws_final[b] = v * LN2;                                             \
            }                                                                      \
            prev[0] = cur0; prev[1] = cur1; prev[2] = cur2; prev[3] = cur3;        \
        }                                                                          \
    }

    for (int ib = 1; ib < N_FRAMES; ib += 4) {
        STEP(0) STEP(1) STEP(2) STEP(3)
    }
#undef STEP
}

extern "C" void kernel_launch(void* const* d_in, const int* in_sizes, int n_in,
                              void* d_out, int out_size, void* d_ws, size_t ws_size,
                              hipStream_t stream)
{
    const float* scores  = (const float*)d_in[0];
    const int*   targets = (const int*)  d_in[1];
    const int*   in_len  = (const int*)  d_in[2];
    const int*   tg_len  = (const int*)  d_in[3];
    float*       out     = (float*)d_out;
    float*       ws_fin  = (float*)d_ws;                     // [0,256): per-batch finals

    const size_t emit_bytes = (size_t)BATCH * N_FRAMES * 1024 * sizeof(__half);
    const size_t wsA_off  = 4096;
    const size_t wsB_off  = wsA_off + (size_t)BATCH * 1024 * sizeof(float);   // +128KB
    const size_t emit_off = wsB_off + (size_t)BATCH * 1024 * sizeof(float);   // +128KB
    const size_t need = emit_off + emit_bytes;

    if (ws_size >= need) {
        __half* emit = (__half*)((char*)d_ws + emit_off);
        float*  wsA  = (float*)((char*)d_ws + wsA_off);
        float*  wsB  = (float*)((char*)d_ws + wsB_off);
        dim3 ggrid((N_FRAMES + RPB - 1) / RPB, BATCH);
        gather_emit3<<<ggrid, 256, 0, stream>>>(scores, targets, in_len, emit);
        align_dp_fb<<<dim3(BATCH, 2), 512, 0, stream>>>(emit, in_len, tg_len, wsA, wsB);
        lse_combine<<<BATCH, 512, 0, stream>>>(wsA, wsB, ws_fin);
    } else {
        align_dp4<<<BATCH, 256, 0, stream>>>(scores, targets, in_len, tg_len, ws_fin);
    }
    reduce_kernel<<<1, 64, 0, stream>>>(ws_fin, out);
}